// Round 10
// baseline (133.604 us; speedup 1.0000x reference)
//
#include <hip/hip_runtime.h>

// ---------- helpers ----------
typedef __bf16 bf16x8 __attribute__((ext_vector_type(8)));
typedef float  f32x4  __attribute__((ext_vector_type(4)));
typedef unsigned short u16x8 __attribute__((ext_vector_type(8)));
typedef unsigned int u32;
typedef unsigned long long u64;

static __device__ __forceinline__ unsigned short f32_to_bf16(float f){
  unsigned u = __float_as_uint(f);
  u += 0x7fffu + ((u >> 16) & 1u);          // round-to-nearest-even
  return (unsigned short)(u >> 16);
}
static __device__ __forceinline__ float bf16_to_f32(unsigned short h){
  return __uint_as_float(((unsigned)h) << 16);
}

#define GLOAD_LDS16(g, l)                                                        \
  __builtin_amdgcn_global_load_lds((const __attribute__((address_space(1))) void*)(g), \
                                   (__attribute__((address_space(3))) void*)(l), 16, 0, 0)

// ---------- K0: weight conversion + BN folding ----------
// w1s PRE-SWIZZLED: element (o,c) at [o][c ^ (((o^(o>>3))&7)<<3)] so conv1's
// linear gload_lds dest gives 2-way-max conflicts on swizzled ds_read_b128.
__global__ __launch_bounds__(256) void prep_kernel(
    const float* __restrict__ w1, const float* __restrict__ w2,
    const float* __restrict__ b1, const float* __restrict__ g1, const float* __restrict__ be1,
    const float* __restrict__ m1, const float* __restrict__ v1,
    const float* __restrict__ b2, const float* __restrict__ g2, const float* __restrict__ be2,
    const float* __restrict__ m2, const float* __restrict__ v2,
    unsigned short* __restrict__ w1s, unsigned short* __restrict__ w2b,
    float* __restrict__ sc1, float* __restrict__ sh1,
    float* __restrict__ sc2, float* __restrict__ sh2)
{
  int i = blockIdx.x * 256 + threadIdx.x;
  int stride = gridDim.x * 256;
  for (int k = i; k < 512 * 2048; k += stride){
    int o = k >> 11, c = k & 2047;
    int key = (o ^ (o >> 3)) & 7;
    w1s[(o << 11) | (c ^ (key << 3))] = f32_to_bf16(w1[k]);
  }
  for (int k = i; k < 256 * 512;  k += stride) w2b[k] = f32_to_bf16(w2[k]);
  if (i < 512){
    float s = g1[i] * rsqrtf(v1[i] + 1e-5f);
    sc1[i] = s;
    sh1[i] = (b1[i] - m1[i]) * s + be1[i];
  } else if (i - 512 < 256){
    int o = i - 512;
    float s = g2[o] * rsqrtf(v2[o] + 1e-5f);
    sc2[o] = s;
    sh2[o] = (b2[o] - m2[o]) * s + be2[o];
  }
}

// ---------- K1: conv1 full map, 8-phase-style 256x256 template port ----------
// Zt[b*4096+p][512] = (W1.F)^T. BM=256p x BN=256o x BK=64, 8 waves of 128x64,
// 128 KB LDS double-buffered, grid 128 (XCD-paired o-tiles). 4 phases/K-tile:
// {ds_read frags | stage issue | barrier | lgkm0 | setprio MFMA x16 | barrier}.
// Counted vmcnt: feat loads waited at vmcnt(4) (phase 2), weight DMA at
// vmcnt(0) (phase 3, issued 3 phases earlier) -- no mid-pipeline full drain.
// LDS map: feat buf b at lds + b*16384 ; weights buf b at lds + 32768 + b*16384.
__global__ __launch_bounds__(512, 1) void conv1_kernel(
    const unsigned short* __restrict__ w1s,   // [512][2048] bf16 pre-swizzled
    const float* __restrict__ feat,           // [4][2048][4096] f32
    unsigned short* __restrict__ zt)          // [4*4096][512] bf16
{
  __shared__ unsigned short lds[65536];       // 128 KB total
  int t = threadIdx.x, l = t & 63, wid = t >> 6;
  int wr = wid >> 2, wc = wid & 3;            // wave tile 128p x 64o

  int lid = ((blockIdx.x & 7) << 4) | (blockIdx.x >> 3);   // bijective XCD swizzle
  int nt = lid & 1, mt = lid >> 1;            // o-tile pair of one p-panel same XCD
  int bb = mt >> 4;
  int p0g = (mt & 15) << 8;
  int o0 = nt << 8;

  // feat staging: thread owns c-rows cs..cs+7 (cs = wid*8), p ps..ps+3
  int cs = wid << 3;
  int ps = (t & 63) << 2;
  const float* fBase = feat + ((size_t)(bb * 2048 + cs)) * 4096 + p0g + ps;

  // weight staging: 4 gload_lds chunks of o+=64
  const unsigned short* wBase = w1s + ((size_t)(o0 + (t >> 3))) * 2048 + (t & 7) * 8;
  int wDstOff = (t >> 3) * 64 + (t & 7) * 8;

  f32x4 acc[8][4];
  #pragma unroll
  for (int m = 0; m < 8; ++m)
    #pragma unroll
    for (int n = 0; n < 4; ++n){ f32x4 z4 = {0.f,0.f,0.f,0.f}; acc[m][n] = z4; }

  f32x4 rF[8];
  bf16x8 af[2][4], bf[2][2];

#define FEAT_LOAD(kt) do {                                                  \
    _Pragma("unroll")                                                       \
    for (int i = 0; i < 8; ++i)                                             \
      rF[i] = *(const f32x4*)(fBase + (size_t)((kt) + i) * 4096);           \
  } while (0)

#define FEAT_WRITE(buf) do {                                                \
    _Pragma("unroll")                                                       \
    for (int j = 0; j < 4; ++j){                                            \
      int p_ = ps + j;                                                      \
      int f_ = (p_ ^ (p_ >> 3)) & 7;                                        \
      int base_ = (buf) * 32768 + p_ * 128 + ((cs * 2) ^ (f_ << 4));        \
      u32 a0 = ((u32)f32_to_bf16(rF[0][j])) | (((u32)f32_to_bf16(rF[1][j])) << 16); \
      u32 a1 = ((u32)f32_to_bf16(rF[2][j])) | (((u32)f32_to_bf16(rF[3][j])) << 16); \
      u32 a2 = ((u32)f32_to_bf16(rF[4][j])) | (((u32)f32_to_bf16(rF[5][j])) << 16); \
      u32 a3 = ((u32)f32_to_bf16(rF[6][j])) | (((u32)f32_to_bf16(rF[7][j])) << 16); \
      *(u64*)((char*)lds + base_)     = ((u64)a1 << 32) | a0;               \
      *(u64*)((char*)lds + base_ + 8) = ((u64)a3 << 32) | a2;               \
    }                                                                       \
  } while (0)

#define WT_DMA(buf, kt) do {                                                \
    _Pragma("unroll")                                                       \
    for (int i = 0; i < 4; ++i)                                             \
      GLOAD_LDS16(wBase + (kt) + (size_t)i * (64 * 2048),                   \
                  lds + 32768 + (buf) * 16384 + wDstOff + i * (64 * 64));   \
  } while (0)

#define READ_A(buf, mh) do {                                                \
    _Pragma("unroll")                                                       \
    for (int ks = 0; ks < 2; ++ks)                                          \
      _Pragma("unroll")                                                     \
      for (int mm = 0; mm < 4; ++mm){                                       \
        int p_ = wr * 128 + ((mh) * 4 + mm) * 16 + (l & 15);                \
        int cb_ = ks * 64 + (l >> 4) * 16;                                  \
        int f_ = (p_ ^ (p_ >> 3)) & 7;                                      \
        af[ks][mm] = *(const bf16x8*)((const char*)lds + (buf) * 32768 + p_ * 128 + (cb_ ^ (f_ << 4))); \
      }                                                                     \
  } while (0)

#define READ_B(buf, nh) do {                                                \
    _Pragma("unroll")                                                       \
    for (int ks = 0; ks < 2; ++ks)                                          \
      _Pragma("unroll")                                                     \
      for (int nn = 0; nn < 2; ++nn){                                       \
        int o_ = wc * 64 + ((nh) * 2 + nn) * 16 + (l & 15);                 \
        int cb_ = ks * 64 + (l >> 4) * 16;                                  \
        int f_ = (o_ ^ (o_ >> 3)) & 7;                                      \
        bf[ks][nn] = *(const bf16x8*)((const char*)lds + 65536 + (buf) * 32768 + o_ * 128 + (cb_ ^ (f_ << 4))); \
      }                                                                     \
  } while (0)

#define MFMA16(mh, nh) do {                                                 \
    __builtin_amdgcn_s_setprio(1);                                          \
    _Pragma("unroll")                                                       \
    for (int ks = 0; ks < 2; ++ks)                                          \
      _Pragma("unroll")                                                     \
      for (int mm = 0; mm < 4; ++mm)                                        \
        _Pragma("unroll")                                                   \
        for (int nn = 0; nn < 2; ++nn)                                      \
          acc[(mh) * 4 + mm][(nh) * 2 + nn] = __builtin_amdgcn_mfma_f32_16x16x32_bf16( \
              af[ks][mm], bf[ks][nn], acc[(mh) * 4 + mm][(nh) * 2 + nn], 0, 0, 0); \
    __builtin_amdgcn_s_setprio(0);                                          \
  } while (0)

#define LGKM0_SB() do {                                                     \
    asm volatile("s_waitcnt lgkmcnt(0)" ::: "memory");                      \
    __builtin_amdgcn_sched_barrier(0);                                      \
  } while (0)

  // prologue: stage tile 0 into buf 0
  FEAT_LOAD(0);
  WT_DMA(0, 0);
  asm volatile("s_waitcnt vmcnt(4)" ::: "memory");   // feat landed, DMA in flight
  __builtin_amdgcn_sched_barrier(0);
  FEAT_WRITE(0);
  asm volatile("s_waitcnt vmcnt(0)" ::: "memory");   // weight DMA landed
  LGKM0_SB();
  __builtin_amdgcn_s_barrier();

  for (int it = 0; it < 32; ++it){
    int cur = it & 1, nxt = cur ^ 1;
    int ktn = (it < 31 ? it + 1 : 31) << 6;          // redundant last prefetch (unread)

    // ---- phase 0: frags(m0-3, n0-1) + issue next-tile loads ----
    READ_A(cur, 0);
    READ_B(cur, 0);
    FEAT_LOAD(ktn);                                  // queue: [feat x8]
    WT_DMA(nxt, ktn);                                // queue: [feat x8, wt x4]
    __builtin_amdgcn_s_barrier();
    LGKM0_SB();
    MFMA16(0, 0);
    __builtin_amdgcn_s_barrier();

    // ---- phase 1: frags(n2-3), compute (m0-3 x n2-3) ----
    READ_B(cur, 1);
    __builtin_amdgcn_s_barrier();
    LGKM0_SB();
    MFMA16(0, 1);
    __builtin_amdgcn_s_barrier();

    // ---- phase 2: frags(m4-7), feat cvt+write (B n2-3 kept in regs) ----
    READ_A(cur, 1);
    asm volatile("s_waitcnt vmcnt(4)" ::: "memory"); // feat loads done; DMA in flight
    __builtin_amdgcn_sched_barrier(0);
    FEAT_WRITE(nxt);
    __builtin_amdgcn_s_barrier();
    LGKM0_SB();
    MFMA16(1, 1);
    __builtin_amdgcn_s_barrier();

    // ---- phase 3: frags(n0-1 re-read), compute (m4-7 x n0-1) ----
    READ_B(cur, 0);
    __builtin_amdgcn_s_barrier();
    LGKM0_SB();
    MFMA16(1, 0);
    asm volatile("s_waitcnt vmcnt(0)" ::: "memory"); // wt DMA (issued 3 phases ago) done
    __builtin_amdgcn_sched_barrier(0);
    __builtin_amdgcn_s_barrier();
  }
  __syncthreads();   // before LDS reuse

  // ---- epilogue: transpose 256p x 256o into lds as [256p][512B], write Zt ----
  #pragma unroll
  for (int m = 0; m < 8; ++m){
    #pragma unroll
    for (int n = 0; n < 4; ++n){
      int o_c = wc * 64 + n * 16 + (l & 15);
      #pragma unroll
      for (int r = 0; r < 4; ++r){
        int p_ = wr * 128 + m * 16 + (l >> 4) * 4 + r;
        *(unsigned short*)((char*)lds + p_ * 512 + ((o_c * 2) ^ ((p_ & 7) << 4))) =
            f32_to_bf16(acc[m][n][r]);
      }
    }
  }
  __syncthreads();
  {
    int p = t >> 1, half = t & 1;
    size_t rowb = ((size_t)(bb * 4096 + p0g + p)) * 1024 + (size_t)o0 * 2 + half * 256;
    int swz = (p & 7) << 4;
    #pragma unroll
    for (int j = 0; j < 16; ++j){
      int y = (half * 256 + j * 16) ^ swz;
      f32x4 v = *(const f32x4*)((char*)lds + p * 512 + y);
      *(f32x4*)((char*)zt + rowb + j * 16) = v;
    }
  }
#undef FEAT_LOAD
#undef FEAT_WRITE
#undef WT_DMA
#undef READ_A
#undef READ_B
#undef MFMA16
#undef LGKM0_SB
}

// ---------- K2: ROI gather on Zt (512 ch) + BN1 + ReLU -> h1 bf16 [6272][512] ----------
__global__ __launch_bounds__(256) void roi_gather_kernel(
    const unsigned short* __restrict__ zt, const float* __restrict__ boxes,
    const float* __restrict__ sc1, const float* __restrict__ sh1,
    unsigned short* __restrict__ h1)
{
  int ky = blockIdx.x, roi = blockIdx.y;
  __shared__ int   sIdx[16][8];
  __shared__ float sW[16][8];
  int t = threadIdx.x;

  int   b   = (int)boxes[roi * 5 + 0];
  float bx1 = boxes[roi * 5 + 1], by1 = boxes[roi * 5 + 2];
  float bx2 = boxes[roi * 5 + 3], by2 = boxes[roi * 5 + 4];
  float rw = fmaxf(bx2 - bx1, 1.f), rh = fmaxf(by2 - by1, 1.f);
  float bw = rw * (1.f / 7.f), bh = rh * (1.f / 7.f);

  if (t < 28){
    int kx = t >> 2, s = t & 3;
    int sy = s >> 1, sx = s & 1;
    float yy = by1 + ((float)ky + ((float)sy + 0.5f) * 0.5f) * bh;
    float xx = bx1 + ((float)kx + ((float)sx + 0.5f) * 0.5f) * bw;
    bool vy = (yy >= -1.f) && (yy <= 64.f);
    bool vx = (xx >= -1.f) && (xx <= 64.f);
    float yc = fminf(fmaxf(yy, 0.f), 63.f);
    float xc = fminf(fmaxf(xx, 0.f), 63.f);
    int iy0 = (int)yc, ix0 = (int)xc;
    int iy1 = min(iy0 + 1, 63), ix1 = min(ix0 + 1, 63);
    float fy = yc - (float)iy0, fx = xc - (float)ix0;
    float v = (vy && vx) ? 0.25f : 0.f;
    float wy0 = 1.f - fy, wx0 = 1.f - fx;
    sIdx[s * 4 + 0][kx] = iy0 * 64 + ix0;  sW[s * 4 + 0][kx] = wy0 * wx0 * v;
    sIdx[s * 4 + 1][kx] = iy0 * 64 + ix1;  sW[s * 4 + 1][kx] = wy0 * fx  * v;
    sIdx[s * 4 + 2][kx] = iy1 * 64 + ix0;  sW[s * 4 + 2][kx] = fy  * wx0 * v;
    sIdx[s * 4 + 3][kx] = iy1 * 64 + ix1;  sW[s * 4 + 3][kx] = fy  * fx  * v;
  }
  __syncthreads();

  int w = t >> 6, l = t & 63;
  f32x4 s0 = *(const f32x4*)(sc1 + l * 8);
  f32x4 s1 = *(const f32x4*)(sc1 + l * 8 + 4);
  f32x4 h0 = *(const f32x4*)(sh1 + l * 8);
  f32x4 hh = *(const f32x4*)(sh1 + l * 8 + 4);
  const unsigned short* zb = zt + ((size_t)b * 4096) * 512 + l * 8;

  for (int kx = w; kx < 7; kx += 4){
    float a[8];
    #pragma unroll
    for (int j = 0; j < 8; ++j) a[j] = 0.f;
    #pragma unroll
    for (int i = 0; i < 16; ++i){
      int idx = sIdx[i][kx];
      float wt = sW[i][kx];
      u16x8 v = *(const u16x8*)(zb + (size_t)idx * 512);
      #pragma unroll
      for (int j = 0; j < 8; ++j) a[j] += wt * bf16_to_f32(v[j]);
    }
    u16x8 o;
    #pragma unroll
    for (int j = 0; j < 4; ++j){
      float v0 = fmaxf(a[j] * s0[j] + h0[j], 0.f);
      float v1 = fmaxf(a[j + 4] * s1[j] + hh[j], 0.f);
      o[j] = f32_to_bf16(v0);
      o[j + 4] = f32_to_bf16(v1);
    }
    *(u16x8*)(h1 + ((size_t)(roi * 49 + ky * 7 + kx)) * 512 + l * 8) = o;
  }
}

// ---------- K3: bf16 GEMM, B-transposed input, fused scale/shift + ReLU ----------
template<int BM, int BN>
__global__ __launch_bounds__(256) void gemm_bt_relu(
    const unsigned short* __restrict__ A, const unsigned short* __restrict__ Bt,
    const float* __restrict__ scale, const float* __restrict__ shift,
    unsigned short* __restrict__ C, int M, int N, int K)
{
  constexpr int BK = 64;
  constexpr int FM = BM / 32;
  constexpr int FN = BN / 32;
  __shared__ unsigned short lds_a[BM * BK];
  __shared__ unsigned short lds_b[BN * BK];
  int t = threadIdx.x;
  int l = t & 63, wid = t >> 6;
  int wr = wid >> 1, wc = wid & 1;
  int m0 = blockIdx.y * BM, n0 = blockIdx.x * BN;

  f32x4 acc[FM][FN];
  f32x4 z = {0.f, 0.f, 0.f, 0.f};
  #pragma unroll
  for (int m = 0; m < FM; ++m)
    #pragma unroll
    for (int n = 0; n < FN; ++n) acc[m][n] = z;

  const unsigned short* Ab = A  + (size_t)m0 * K;
  const unsigned short* Bb = Bt + (size_t)n0 * K;

  for (int kt = 0; kt < K; kt += BK){
    #pragma unroll
    for (int r = 0; r < BM / 32; ++r){
      int row = r * 32 + (t >> 3);
      GLOAD_LDS16(Ab + (size_t)row * K + kt + (t & 7) * 8,
                  lds_a + row * BK + (t & 7) * 8);
    }
    #pragma unroll
    for (int r = 0; r < BN / 32; ++r){
      int row = r * 32 + (t >> 3);
      GLOAD_LDS16(Bb + (size_t)row * K + kt + (t & 7) * 8,
                  lds_b + row * BK + (t & 7) * 8);
    }
    __syncthreads();
    #pragma unroll
    for (int ks = 0; ks < 2; ++ks){
      bf16x8 af[FM], bfr[FN];
      #pragma unroll
      for (int m = 0; m < FM; ++m)
        af[m] = *reinterpret_cast<const bf16x8*>(
            lds_a + (wr * (BM / 2) + m * 16 + (l & 15)) * BK + ks * 32 + (l >> 4) * 8);
      #pragma unroll
      for (int n = 0; n < FN; ++n)
        bfr[n] = *reinterpret_cast<const bf16x8*>(
            lds_b + (wc * (BN / 2) + n * 16 + (l & 15)) * BK + ks * 32 + (l >> 4) * 8);
      #pragma unroll
      for (int m = 0; m < FM; ++m)
        #pragma unroll
        for (int n = 0; n < FN; ++n)
          acc[m][n] = __builtin_amdgcn_mfma_f32_16x16x32_bf16(af[m], bfr[n], acc[m][n], 0, 0, 0);
    }
    __syncthreads();
  }

  #pragma unroll
  for (int m = 0; m < FM; ++m){
    int gr = m0 + wr * (BM / 2) + m * 16 + (l >> 4) * 4;
    #pragma unroll
    for (int n = 0; n < FN; ++n){
      int gc = n0 + wc * (BN / 2) + n * 16 + (l & 15);
      float sc = scale[gc], sh = shift[gc];
      #pragma unroll
      for (int r = 0; r < 4; ++r){
        float v = acc[m][n][r] * sc + sh;
        v = fmaxf(v, 0.f);
        C[(size_t)(gr + r) * N + gc] = f32_to_bf16(v);
      }
    }
  }
}

// ---------- K4: mean over 49 bins -> out f32 [128][256] ----------
__global__ __launch_bounds__(256) void reduce_kernel(
    const unsigned short* __restrict__ h2, float* __restrict__ out)
{
  int n = blockIdx.x, o = threadIdx.x;
  const unsigned short* p = h2 + (size_t)n * 49 * 256 + o;
  float s = 0.f;
  for (int j = 0; j < 49; ++j) s += bf16_to_f32(p[j * 256]);
  out[n * 256 + o] = s * (1.f / 49.f);
}

// ---------- launch ----------
extern "C" void kernel_launch(void* const* d_in, const int* in_sizes, int n_in,
                              void* d_out, int out_size, void* d_ws, size_t ws_size,
                              hipStream_t stream)
{
  const float* feat  = (const float*)d_in[0];
  const float* boxes = (const float*)d_in[1];
  const float* w1  = (const float*)d_in[2];
  const float* b1  = (const float*)d_in[3];
  const float* g1  = (const float*)d_in[4];
  const float* be1 = (const float*)d_in[5];
  const float* m1  = (const float*)d_in[6];
  const float* v1  = (const float*)d_in[7];
  const float* w2  = (const float*)d_in[8];
  const float* b2  = (const float*)d_in[9];
  const float* g2  = (const float*)d_in[10];
  const float* be2 = (const float*)d_in[11];
  const float* m2  = (const float*)d_in[12];
  const float* v2  = (const float*)d_in[13];
  float* out = (float*)d_out;

  char* ws = (char*)d_ws;
  unsigned short* w1s = (unsigned short*)(ws);                         // 2 MB (pre-swizzled)
  unsigned short* w2b = (unsigned short*)(ws + (2u << 20));            // 256 KB
  float* sc1 = (float*)(ws + (2u << 20) + (256u << 10));
  float* sh1 = sc1 + 512;
  float* sc2 = sh1 + 512;
  float* sh2 = sc2 + 256;
  unsigned short* zt = (unsigned short*)(ws + (4u  << 20));            // 16.8 MB
  unsigned short* h1 = (unsigned short*)(ws + (24u << 20));            // 6.4 MB
  unsigned short* h2 = (unsigned short*)(ws + (32u << 20));            // 3.2 MB

  hipLaunchKernelGGL(prep_kernel, dim3(256), dim3(256), 0, stream,
                     w1, w2, b1, g1, be1, m1, v1, b2, g2, be2, m2, v2,
                     w1s, w2b, sc1, sh1, sc2, sh2);
  hipLaunchKernelGGL(conv1_kernel, dim3(128), dim3(512), 0, stream,
                     w1s, feat, zt);
  hipLaunchKernelGGL(roi_gather_kernel, dim3(7, 128), dim3(256), 0, stream,
                     zt, boxes, sc1, sh1, h1);
  hipLaunchKernelGGL(HIP_KERNEL_NAME(gemm_bt_relu<64, 64>),
                     dim3(256 / 64, 6272 / 64), dim3(256), 0, stream,
                     h1, w2b, sc2, sh2, h2, 6272, 256, 512);
  hipLaunchKernelGGL(reduce_kernel, dim3(128), dim3(256), 0, stream, h2, out);
}

// Round 11
// 91.557 us; speedup vs baseline: 1.4592x; 1.4592x over previous
//
#include <hip/hip_runtime.h>

// ---------- helpers ----------
typedef __bf16 bf16x8 __attribute__((ext_vector_type(8)));
typedef float  f32x4  __attribute__((ext_vector_type(4)));
typedef unsigned short u16x8 __attribute__((ext_vector_type(8)));
typedef unsigned int u32;
typedef unsigned long long u64;

static __device__ __forceinline__ unsigned short f2bf(float f){
  __bf16 b = (__bf16)f;                     // native cvt (RTNE); compiler pairs into v_cvt_pk_bf16_f32
  return *(unsigned short*)&b;
}
static __device__ __forceinline__ float bf16_to_f32(unsigned short h){
  return __uint_as_float(((unsigned)h) << 16);
}

#define GLOAD_LDS16(g, l)                                                        \
  __builtin_amdgcn_global_load_lds((const __attribute__((address_space(1))) void*)(g), \
                                   (__attribute__((address_space(3))) void*)(l), 16, 0, 0)

// ---------- K0: weight conversion + BN folding ----------
// w1s PRE-SWIZZLED: element (o,c) at [o][c ^ (((o^(o>>3))&7)<<3)] so conv1's
// linear gload_lds dest gives low-conflict swizzled ds_read_b128.
__global__ __launch_bounds__(256) void prep_kernel(
    const float* __restrict__ w1, const float* __restrict__ w2,
    const float* __restrict__ b1, const float* __restrict__ g1, const float* __restrict__ be1,
    const float* __restrict__ m1, const float* __restrict__ v1,
    const float* __restrict__ b2, const float* __restrict__ g2, const float* __restrict__ be2,
    const float* __restrict__ m2, const float* __restrict__ v2,
    unsigned short* __restrict__ w1s, unsigned short* __restrict__ w2b,
    float* __restrict__ sc1, float* __restrict__ sh1,
    float* __restrict__ sc2, float* __restrict__ sh2)
{
  int i = blockIdx.x * 256 + threadIdx.x;
  int stride = gridDim.x * 256;
  for (int k = i; k < 512 * 2048; k += stride){
    int o = k >> 11, c = k & 2047;
    int key = (o ^ (o >> 3)) & 7;
    w1s[(o << 11) | (c ^ (key << 3))] = f2bf(w1[k]);
  }
  for (int k = i; k < 256 * 512;  k += stride) w2b[k] = f2bf(w2[k]);
  if (i < 512){
    float s = g1[i] * rsqrtf(v1[i] + 1e-5f);
    sc1[i] = s;
    sh1[i] = (b1[i] - m1[i]) * s + be1[i];
  } else if (i - 512 < 256){
    int o = i - 512;
    float s = g2[o] * rsqrtf(v2[o] + 1e-5f);
    sc2[o] = s;
    sh2[o] = (b2[o] - m2[o]) * s + be2[o];
  }
}

// ---------- K1: conv1 full map: Zt[b*4096+p][512] = (W1.F)^T, bf16 ----------
// BM=128p x BN=256o x BK=64, 8 waves of 64x64, grid 256 (1 block/CU, ALL CUs),
// 96 KB LDS double-buffered. 2 interleaved phases per K-tile:
//  P0: ds_read A(m0-3)+B(n0-1) | issue WT_DMA(next), FEAT_LOAD(dist-2) | bar |
//      lgkm0 | setprio 16 MFMA | bar
//  P1: ds_read B(n2-3) | feat cvt+ds_write(next) | bar | lgkm0 | setprio
//      16 MFMA | vmcnt(4) (wt DMA done; feat prefetch stays in flight) | bar
// vmcnt queue kept as [wt4, feat4] (wt issued first) so the counted wait
// releases the weight buffer without draining the HBM feat prefetch.
// LDS map (ushort units): A buf b @ b*8192 (128x64) ; B buf b @ 16384+b*16384.
__global__ __launch_bounds__(512, 1) void conv1_kernel(
    const unsigned short* __restrict__ w1s,   // [512][2048] bf16 pre-swizzled
    const float* __restrict__ feat,           // [4][2048][4096] f32
    unsigned short* __restrict__ zt)          // [4*4096][512] bf16
{
  __shared__ unsigned short lds[49152];       // 96 KB
  int t = threadIdx.x, l = t & 63, wid = t >> 6;
  int wr = wid >> 2, wc = wid & 3;            // wave tile 64p x 64o

  int lid = ((blockIdx.x & 7) << 5) | (blockIdx.x >> 3);   // bijective XCD swizzle (256=8x32)
  int nt = lid & 1, mt = lid >> 1;            // o-halves of one p-panel adjacent on XCD
  int bb = mt >> 5;
  int p0g = (mt & 31) << 7;
  int o0 = nt << 8;

  // feat staging: thread owns c-rows c4..c4+3, f32x4 at p4
  int c4 = (t >> 5) << 2;                     // 0..60
  int p4 = (t & 31) << 2;                     // 0..124
  const float* fBase = feat + ((size_t)(bb * 2048 + c4)) * 4096 + p0g + p4;

  // weight staging: 4 gload_lds chunks (o += 64 each)
  const unsigned short* wBase = w1s + ((size_t)(o0 + (t >> 3))) * 2048 + (t & 7) * 8;
  int wDstOff = (t >> 3) * 64 + (t & 7) * 8;

  f32x4 acc[4][4];
  #pragma unroll
  for (int m = 0; m < 4; ++m)
    #pragma unroll
    for (int n = 0; n < 4; ++n){ f32x4 z4 = {0.f,0.f,0.f,0.f}; acc[m][n] = z4; }

  f32x4 rFa[4], rFb[4];
  bf16x8 af[2][4], bfrag[2][2];

#define FEAT_LOAD(dst, kt) do {                                             \
    _Pragma("unroll")                                                       \
    for (int i = 0; i < 4; ++i)                                             \
      dst[i] = *(const f32x4*)(fBase + (size_t)((kt) + i) * 4096);          \
  } while (0)

#define FEAT_WRITE(buf, src) do {                                           \
    _Pragma("unroll")                                                       \
    for (int j = 0; j < 4; ++j){                                            \
      int p_ = p4 + j;                                                      \
      int f_ = (p_ ^ (p_ >> 3)) & 7;                                        \
      u32 lo_ = ((u32)f2bf(src[0][j])) | (((u32)f2bf(src[1][j])) << 16);    \
      u32 hi_ = ((u32)f2bf(src[2][j])) | (((u32)f2bf(src[3][j])) << 16);    \
      u64 v_ = ((u64)hi_ << 32) | lo_;                                      \
      *(u64*)((char*)lds + (buf) * 16384 + p_ * 128 + ((c4 * 2) ^ (f_ << 4))) = v_; \
    }                                                                       \
  } while (0)

#define WT_DMA(buf, kt) do {                                                \
    _Pragma("unroll")                                                       \
    for (int i = 0; i < 4; ++i)                                             \
      GLOAD_LDS16(wBase + (kt) + (size_t)i * (64 * 2048),                   \
                  lds + 16384 + (buf) * 16384 + wDstOff + i * (64 * 64));   \
  } while (0)

#define READ_A(buf) do {                                                    \
    _Pragma("unroll")                                                       \
    for (int ks = 0; ks < 2; ++ks)                                          \
      _Pragma("unroll")                                                     \
      for (int mm = 0; mm < 4; ++mm){                                       \
        int p_ = wr * 64 + mm * 16 + (l & 15);                              \
        int cb_ = ks * 64 + (l >> 4) * 16;                                  \
        int f_ = (p_ ^ (p_ >> 3)) & 7;                                      \
        af[ks][mm] = *(const bf16x8*)((const char*)lds + (buf) * 16384 + p_ * 128 + (cb_ ^ (f_ << 4))); \
      }                                                                     \
  } while (0)

#define READ_B(buf, nh) do {                                                \
    _Pragma("unroll")                                                       \
    for (int ks = 0; ks < 2; ++ks)                                          \
      _Pragma("unroll")                                                     \
      for (int nn = 0; nn < 2; ++nn){                                       \
        int o_ = wc * 64 + ((nh) * 2 + nn) * 16 + (l & 15);                 \
        int cb_ = ks * 64 + (l >> 4) * 16;                                  \
        int f_ = (o_ ^ (o_ >> 3)) & 7;                                      \
        bfrag[ks][nn] = *(const bf16x8*)((const char*)lds + 32768 + (buf) * 32768 + o_ * 128 + (cb_ ^ (f_ << 4))); \
      }                                                                     \
  } while (0)

#define MFMA16(nh) do {                                                     \
    __builtin_amdgcn_s_setprio(1);                                          \
    _Pragma("unroll")                                                       \
    for (int ks = 0; ks < 2; ++ks)                                          \
      _Pragma("unroll")                                                     \
      for (int mm = 0; mm < 4; ++mm)                                        \
        _Pragma("unroll")                                                   \
        for (int nn = 0; nn < 2; ++nn)                                      \
          acc[mm][(nh) * 2 + nn] = __builtin_amdgcn_mfma_f32_16x16x32_bf16( \
              af[ks][mm], bfrag[ks][nn], acc[mm][(nh) * 2 + nn], 0, 0, 0);  \
    __builtin_amdgcn_s_setprio(0);                                          \
  } while (0)

#define LGKM0_SB() do {                                                     \
    asm volatile("s_waitcnt lgkmcnt(0)" ::: "memory");                      \
    __builtin_amdgcn_sched_barrier(0);                                      \
  } while (0)

#define TILE_BODY(cur, rWr, rLd, ktWt, ktFt) do {                           \
    /* P0 */                                                                \
    READ_A(cur);                                                            \
    READ_B(cur, 0);                                                         \
    WT_DMA((cur) ^ 1, (ktWt));          /* queue: [wt 4] */                 \
    FEAT_LOAD(rLd, (ktFt));             /* queue: [wt 4, feat 4] */         \
    __builtin_amdgcn_s_barrier();                                           \
    LGKM0_SB();                                                             \
    MFMA16(0);                                                              \
    __builtin_amdgcn_s_barrier();                                           \
    /* P1 */                                                                \
    READ_B(cur, 1);                                                         \
    FEAT_WRITE((cur) ^ 1, rWr);         /* reg scoreboard waits rWr only */ \
    __builtin_amdgcn_s_barrier();                                           \
    LGKM0_SB();                                                             \
    MFMA16(1);                                                              \
    asm volatile("s_waitcnt vmcnt(4)" ::: "memory");  /* wt done; feat flies */ \
    __builtin_amdgcn_sched_barrier(0);                                      \
    __builtin_amdgcn_s_barrier();                                           \
  } while (0)

  // prologue: tile0 staged to buf0; tile1 feat in rFb
  FEAT_LOAD(rFa, 0);
  WT_DMA(0, 0);
  FEAT_LOAD(rFb, 64);
  FEAT_WRITE(0, rFa);                     // auto-waits rFa
  asm volatile("s_waitcnt vmcnt(4)" ::: "memory");   // wt0 done; feat1 in flight
  LGKM0_SB();
  __builtin_amdgcn_s_barrier();

  #pragma unroll 1
  for (int it2 = 0; it2 < 16; ++it2){
    int k0 = it2 << 1;                                    // even tile (buf0)
    int wtE = (k0 + 1 < 32 ? k0 + 1 : 31) << 6;
    int ftE = (k0 + 2 < 32 ? k0 + 2 : 31) << 6;
    TILE_BODY(0, rFb, rFa, wtE, ftE);
    int wtO = (k0 + 2 < 32 ? k0 + 2 : 31) << 6;           // odd tile (buf1)
    int ftO = (k0 + 3 < 32 ? k0 + 3 : 31) << 6;
    TILE_BODY(1, rFa, rFb, wtO, ftO);
  }
  __syncthreads();   // drain; lds reused below

  // epilogue: stage 128p x 256o transposed into lds as [128p][512B], write Zt
  #pragma unroll
  for (int m = 0; m < 4; ++m){
    #pragma unroll
    for (int n = 0; n < 4; ++n){
      int o_c = wc * 64 + n * 16 + (l & 15);
      #pragma unroll
      for (int r = 0; r < 4; ++r){
        int p_ = wr * 64 + m * 16 + (l >> 4) * 4 + r;
        *(unsigned short*)((char*)lds + p_ * 512 + ((o_c * 2) ^ ((p_ & 7) << 4))) =
            f2bf(acc[m][n][r]);
      }
    }
  }
  __syncthreads();
  {
    int p = t >> 2, seg = t & 3;
    size_t rowb = ((size_t)(bb * 4096 + p0g + p)) * 1024 + (size_t)o0 * 2 + seg * 128;
    int swz = (p & 7) << 4;
    #pragma unroll
    for (int j = 0; j < 8; ++j){
      int y = (seg * 128 + j * 16) ^ swz;
      f32x4 v = *(const f32x4*)((char*)lds + p * 512 + y);
      *(f32x4*)((char*)zt + rowb + j * 16) = v;
    }
  }
#undef FEAT_LOAD
#undef FEAT_WRITE
#undef WT_DMA
#undef READ_A
#undef READ_B
#undef MFMA16
#undef LGKM0_SB
#undef TILE_BODY
}

// ---------- K2: ROI gather on Zt (512 ch) + BN1 + ReLU -> h1 bf16 [6272][512] ----------
__global__ __launch_bounds__(256) void roi_gather_kernel(
    const unsigned short* __restrict__ zt, const float* __restrict__ boxes,
    const float* __restrict__ sc1, const float* __restrict__ sh1,
    unsigned short* __restrict__ h1)
{
  int ky = blockIdx.x, roi = blockIdx.y;
  __shared__ int   sIdx[16][8];
  __shared__ float sW[16][8];
  int t = threadIdx.x;

  int   b   = (int)boxes[roi * 5 + 0];
  float bx1 = boxes[roi * 5 + 1], by1 = boxes[roi * 5 + 2];
  float bx2 = boxes[roi * 5 + 3], by2 = boxes[roi * 5 + 4];
  float rw = fmaxf(bx2 - bx1, 1.f), rh = fmaxf(by2 - by1, 1.f);
  float bw = rw * (1.f / 7.f), bh = rh * (1.f / 7.f);

  if (t < 28){
    int kx = t >> 2, s = t & 3;
    int sy = s >> 1, sx = s & 1;
    float yy = by1 + ((float)ky + ((float)sy + 0.5f) * 0.5f) * bh;
    float xx = bx1 + ((float)kx + ((float)sx + 0.5f) * 0.5f) * bw;
    bool vy = (yy >= -1.f) && (yy <= 64.f);
    bool vx = (xx >= -1.f) && (xx <= 64.f);
    float yc = fminf(fmaxf(yy, 0.f), 63.f);
    float xc = fminf(fmaxf(xx, 0.f), 63.f);
    int iy0 = (int)yc, ix0 = (int)xc;
    int iy1 = min(iy0 + 1, 63), ix1 = min(ix0 + 1, 63);
    float fy = yc - (float)iy0, fx = xc - (float)ix0;
    float v = (vy && vx) ? 0.25f : 0.f;
    float wy0 = 1.f - fy, wx0 = 1.f - fx;
    sIdx[s * 4 + 0][kx] = iy0 * 64 + ix0;  sW[s * 4 + 0][kx] = wy0 * wx0 * v;
    sIdx[s * 4 + 1][kx] = iy0 * 64 + ix1;  sW[s * 4 + 1][kx] = wy0 * fx  * v;
    sIdx[s * 4 + 2][kx] = iy1 * 64 + ix0;  sW[s * 4 + 2][kx] = fy  * wx0 * v;
    sIdx[s * 4 + 3][kx] = iy1 * 64 + ix1;  sW[s * 4 + 3][kx] = fy  * fx  * v;
  }
  __syncthreads();

  int w = t >> 6, l = t & 63;
  f32x4 s0 = *(const f32x4*)(sc1 + l * 8);
  f32x4 s1 = *(const f32x4*)(sc1 + l * 8 + 4);
  f32x4 h0 = *(const f32x4*)(sh1 + l * 8);
  f32x4 hh = *(const f32x4*)(sh1 + l * 8 + 4);
  const unsigned short* zb = zt + ((size_t)b * 4096) * 512 + l * 8;

  for (int kx = w; kx < 7; kx += 4){
    float a[8];
    #pragma unroll
    for (int j = 0; j < 8; ++j) a[j] = 0.f;
    #pragma unroll
    for (int i = 0; i < 16; ++i){
      int idx = sIdx[i][kx];
      float wt = sW[i][kx];
      u16x8 v = *(const u16x8*)(zb + (size_t)idx * 512);
      #pragma unroll
      for (int j = 0; j < 8; ++j) a[j] += wt * bf16_to_f32(v[j]);
    }
    u16x8 o;
    #pragma unroll
    for (int j = 0; j < 4; ++j){
      float v0 = fmaxf(a[j] * s0[j] + h0[j], 0.f);
      float v1 = fmaxf(a[j + 4] * s1[j] + hh[j], 0.f);
      o[j] = f2bf(v0);
      o[j + 4] = f2bf(v1);
    }
    *(u16x8*)(h1 + ((size_t)(roi * 49 + ky * 7 + kx)) * 512 + l * 8) = o;
  }
}

// ---------- K3: bf16 GEMM, B-transposed input, fused scale/shift + ReLU ----------
template<int BM, int BN>
__global__ __launch_bounds__(256) void gemm_bt_relu(
    const unsigned short* __restrict__ A, const unsigned short* __restrict__ Bt,
    const float* __restrict__ scale, const float* __restrict__ shift,
    unsigned short* __restrict__ C, int M, int N, int K)
{
  constexpr int BK = 64;
  constexpr int FM = BM / 32;
  constexpr int FN = BN / 32;
  __shared__ unsigned short lds_a[BM * BK];
  __shared__ unsigned short lds_b[BN * BK];
  int t = threadIdx.x;
  int l = t & 63, wid = t >> 6;
  int wr = wid >> 1, wc = wid & 1;
  int m0 = blockIdx.y * BM, n0 = blockIdx.x * BN;

  f32x4 acc[FM][FN];
  f32x4 z = {0.f, 0.f, 0.f, 0.f};
  #pragma unroll
  for (int m = 0; m < FM; ++m)
    #pragma unroll
    for (int n = 0; n < FN; ++n) acc[m][n] = z;

  const unsigned short* Ab = A  + (size_t)m0 * K;
  const unsigned short* Bb = Bt + (size_t)n0 * K;

  for (int kt = 0; kt < K; kt += BK){
    #pragma unroll
    for (int r = 0; r < BM / 32; ++r){
      int row = r * 32 + (t >> 3);
      GLOAD_LDS16(Ab + (size_t)row * K + kt + (t & 7) * 8,
                  lds_a + row * BK + (t & 7) * 8);
    }
    #pragma unroll
    for (int r = 0; r < BN / 32; ++r){
      int row = r * 32 + (t >> 3);
      GLOAD_LDS16(Bb + (size_t)row * K + kt + (t & 7) * 8,
                  lds_b + row * BK + (t & 7) * 8);
    }
    __syncthreads();
    #pragma unroll
    for (int ks = 0; ks < 2; ++ks){
      bf16x8 af[FM], bfr[FN];
      #pragma unroll
      for (int m = 0; m < FM; ++m)
        af[m] = *reinterpret_cast<const bf16x8*>(
            lds_a + (wr * (BM / 2) + m * 16 + (l & 15)) * BK + ks * 32 + (l >> 4) * 8);
      #pragma unroll
      for (int n = 0; n < FN; ++n)
        bfr[n] = *reinterpret_cast<const bf16x8*>(
            lds_b + (wc * (BN / 2) + n * 16 + (l & 15)) * BK + ks * 32 + (l >> 4) * 8);
      #pragma unroll
      for (int m = 0; m < FM; ++m)
        #pragma unroll
        for (int n = 0; n < FN; ++n)
          acc[m][n] = __builtin_amdgcn_mfma_f32_16x16x32_bf16(af[m], bfr[n], acc[m][n], 0, 0, 0);
    }
    __syncthreads();
  }

  #pragma unroll
  for (int m = 0; m < FM; ++m){
    int gr = m0 + wr * (BM / 2) + m * 16 + (l >> 4) * 4;
    #pragma unroll
    for (int n = 0; n < FN; ++n){
      int gc = n0 + wc * (BN / 2) + n * 16 + (l & 15);
      float sc = scale[gc], sh = shift[gc];
      #pragma unroll
      for (int r = 0; r < 4; ++r){
        float v = acc[m][n][r] * sc + sh;
        v = fmaxf(v, 0.f);
        C[(size_t)(gr + r) * N + gc] = f2bf(v);
      }
    }
  }
}

// ---------- K4: mean over 49 bins -> out f32 [128][256] ----------
__global__ __launch_bounds__(256) void reduce_kernel(
    const unsigned short* __restrict__ h2, float* __restrict__ out)
{
  int n = blockIdx.x, o = threadIdx.x;
  const unsigned short* p = h2 + (size_t)n * 49 * 256 + o;
  float s = 0.f;
  for (int j = 0; j < 49; ++j) s += bf16_to_f32(p[j * 256]);
  out[n * 256 + o] = s * (1.f / 49.f);
}

// ---------- launch ----------
extern "C" void kernel_launch(void* const* d_in, const int* in_sizes, int n_in,
                              void* d_out, int out_size, void* d_ws, size_t ws_size,
                              hipStream_t stream)
{
  const float* feat  = (const float*)d_in[0];
  const float* boxes = (const float*)d_in[1];
  const float* w1  = (const float*)d_in[2];
  const float* b1  = (const float*)d_in[3];
  const float* g1  = (const float*)d_in[4];
  const float* be1 = (const float*)d_in[5];
  const float* m1  = (const float*)d_in[6];
  const float* v1  = (const float*)d_in[7];
  const float* w2  = (const float*)d_in[8];
  const float* b2  = (const float*)d_in[9];
  const float* g2  = (const float*)d_in[10];
  const float* be2 = (const float*)d_in[11];
  const float* m2  = (const float*)d_in[12];
  const float* v2  = (const float*)d_in[13];
  float* out = (float*)d_out;

  char* ws = (char*)d_ws;
  unsigned short* w1s = (unsigned short*)(ws);                         // 2 MB (pre-swizzled)
  unsigned short* w2b = (unsigned short*)(ws + (2u << 20));            // 256 KB
  float* sc1 = (float*)(ws + (2u << 20) + (256u << 10));
  float* sh1 = sc1 + 512;
  float* sc2 = sh1 + 512;
  float* sh2 = sc2 + 256;
  unsigned short* zt = (unsigned short*)(ws + (4u  << 20));            // 16.8 MB
  unsigned short* h1 = (unsigned short*)(ws + (24u << 20));            // 6.4 MB
  unsigned short* h2 = (unsigned short*)(ws + (32u << 20));            // 3.2 MB

  hipLaunchKernelGGL(prep_kernel, dim3(256), dim3(256), 0, stream,
                     w1, w2, b1, g1, be1, m1, v1, b2, g2, be2, m2, v2,
                     w1s, w2b, sc1, sh1, sc2, sh2);
  hipLaunchKernelGGL(conv1_kernel, dim3(256), dim3(512), 0, stream,
                     w1s, feat, zt);
  hipLaunchKernelGGL(roi_gather_kernel, dim3(7, 128), dim3(256), 0, stream,
                     zt, boxes, sc1, sh1, h1);
  hipLaunchKernelGGL(HIP_KERNEL_NAME(gemm_bt_relu<64, 64>),
                     dim3(256 / 64, 6272 / 64), dim3(256), 0, stream,
                     h1, w2b, sc2, sh2, h2, 6272, 256, 512);
  hipLaunchKernelGGL(reduce_kernel, dim3(128), dim3(256), 0, stream, h2, out);
}

// Round 12
// 80.514 us; speedup vs baseline: 1.6594x; 1.1372x over previous
//
#include <hip/hip_runtime.h>

// ---------- helpers ----------
typedef __bf16 bf16x8 __attribute__((ext_vector_type(8)));
typedef float  f32x4  __attribute__((ext_vector_type(4)));
typedef unsigned short u16x8 __attribute__((ext_vector_type(8)));
typedef unsigned int u32;
typedef unsigned long long u64;

static __device__ __forceinline__ unsigned short f2bf(float f){
  __bf16 b = (__bf16)f;                     // native RTNE cvt; pairs into v_cvt_pk_bf16_f32
  return *(unsigned short*)&b;
}
static __device__ __forceinline__ float bf16_to_f32(unsigned short h){
  return __uint_as_float(((unsigned)h) << 16);
}

#define GLOAD_LDS16(g, l)                                                        \
  __builtin_amdgcn_global_load_lds((const __attribute__((address_space(1))) void*)(g), \
                                   (__attribute__((address_space(3))) void*)(l), 16, 0, 0)

// ---------- K0: weight conversion + BN folding ----------
// w1s PRE-SWIZZLED: element (o,c) at [o][c ^ (((o^(o>>3))&7)<<3)] so conv1's
// linear gload_lds dest gives ~2-way conflicts on swizzled ds_read_b128.
__global__ __launch_bounds__(256) void prep_kernel(
    const float* __restrict__ w1, const float* __restrict__ w2,
    const float* __restrict__ b1, const float* __restrict__ g1, const float* __restrict__ be1,
    const float* __restrict__ m1, const float* __restrict__ v1,
    const float* __restrict__ b2, const float* __restrict__ g2, const float* __restrict__ be2,
    const float* __restrict__ m2, const float* __restrict__ v2,
    unsigned short* __restrict__ w1s, unsigned short* __restrict__ w2b,
    float* __restrict__ sc1, float* __restrict__ sh1,
    float* __restrict__ sc2, float* __restrict__ sh2)
{
  int i = blockIdx.x * 256 + threadIdx.x;
  int stride = gridDim.x * 256;
  for (int k = i; k < 512 * 2048; k += stride){
    int o = k >> 11, c = k & 2047;
    int key = (o ^ (o >> 3)) & 7;
    w1s[(o << 11) | (c ^ (key << 3))] = f2bf(w1[k]);
  }
  for (int k = i; k < 256 * 512;  k += stride) w2b[k] = f2bf(w2[k]);
  if (i < 512){
    float s = g1[i] * rsqrtf(v1[i] + 1e-5f);
    sc1[i] = s;
    sh1[i] = (b1[i] - m1[i]) * s + be1[i];
  } else if (i - 512 < 256){
    int o = i - 512;
    float s = g2[o] * rsqrtf(v2[o] + 1e-5f);
    sc2[o] = s;
    sh2[o] = (b2[o] - m2[o]) * s + be2[o];
  }
}

// ---------- K1: conv1 full map: Zt[b*4096+p][512] = (W1.F)^T, bf16 ----------
// BM=128p x BN=256o x BK=64, 8 waves of 64x64, grid 256 (1 block/CU, all CUs).
// ONE barrier per K-tile, 32 MFMA per barrier. Deep prefetch: weights
// TRI-buffered LDS, DMA issued at tile t for t+2 (~2 tiles in flight); feat
// reg double-set at distance 2. Per tile, vmcnt(8) retires exactly wt(t+1)
// (issue order feat(t+2) then wt(t+2) keeps the in-order count exact).
// LDS (ushort idx): A buf a @ a*8192 (16KB ea); wt buf w @ 16384+w*16384 (32KB ea).
__global__ __launch_bounds__(512, 1) void conv1_kernel(
    const unsigned short* __restrict__ w1s,   // [512][2048] bf16 pre-swizzled
    const float* __restrict__ feat,           // [4][2048][4096] f32
    unsigned short* __restrict__ zt)          // [4*4096][512] bf16
{
  __shared__ unsigned short lds[65536];       // 128 KB
  int t = threadIdx.x, l = t & 63, wid = t >> 6;
  int wr = wid >> 2, wc = wid & 3;            // 2p x 4o wave grid; wave = 64p x 64o

  int lid = ((blockIdx.x & 7) << 5) | (blockIdx.x >> 3);  // bijective XCD swizzle
  int nt = lid & 1, mt = lid >> 1;            // o-halves adjacent on one XCD
  int bb = mt >> 5;
  int p0g = (mt & 31) << 7;
  int o0 = nt << 8;

  // feat staging: thread owns c-rows c4..c4+3, f32x4 at p4
  int c4 = (t >> 5) << 2;                     // 0..60
  int p4 = (t & 31) << 2;                     // 0..124
  const float* fBase = feat + ((size_t)(bb * 2048 + c4)) * 4096 + p0g + p4;

  // weight staging: 4 gload_lds chunks (o += 64 each) into one 32KB buf
  const unsigned short* wBase = w1s + ((size_t)(o0 + (t >> 3))) * 2048 + (t & 7) * 8;
  int wDstOff = (t >> 3) * 64 + (t & 7) * 8;

  f32x4 acc[4][4];
  #pragma unroll
  for (int m = 0; m < 4; ++m)
    #pragma unroll
    for (int n = 0; n < 4; ++n){ f32x4 z4 = {0.f,0.f,0.f,0.f}; acc[m][n] = z4; }

  f32x4 rA[4], rB[4];

#define FEAT_LOAD(dst, kt) do {                                             \
    _Pragma("unroll")                                                       \
    for (int i = 0; i < 4; ++i)                                             \
      dst[i] = *(const f32x4*)(fBase + (size_t)((kt) + i) * 4096);          \
  } while (0)

#define FEAT_WRITE(abuf, src) do {                                          \
    _Pragma("unroll")                                                       \
    for (int j = 0; j < 4; ++j){                                            \
      int p_ = p4 + j;                                                      \
      int f_ = (p_ ^ (p_ >> 3)) & 7;                                        \
      u32 lo_ = ((u32)f2bf(src[0][j])) | (((u32)f2bf(src[1][j])) << 16);    \
      u32 hi_ = ((u32)f2bf(src[2][j])) | (((u32)f2bf(src[3][j])) << 16);    \
      u64 v_ = ((u64)hi_ << 32) | lo_;                                      \
      *(u64*)((char*)lds + (abuf) * 16384 + p_ * 128 + ((c4 * 2) ^ (f_ << 4))) = v_; \
    }                                                                       \
  } while (0)

#define WT_DMA(wbuf, kt) do {                                               \
    _Pragma("unroll")                                                       \
    for (int i = 0; i < 4; ++i)                                             \
      GLOAD_LDS16(wBase + (kt) + (size_t)i * (64 * 2048),                   \
                  lds + 16384 + (wbuf) * 16384 + wDstOff + i * (64 * 64));  \
  } while (0)

#define READ_FRAGS(abuf, wbuf) do {                                         \
    _Pragma("unroll")                                                       \
    for (int ks = 0; ks < 2; ++ks){                                         \
      int cb_ = ks * 64 + (l >> 4) * 16;                                    \
      _Pragma("unroll")                                                     \
      for (int mm = 0; mm < 4; ++mm){                                       \
        int p_ = wr * 64 + mm * 16 + (l & 15);                              \
        int f_ = (p_ ^ (p_ >> 3)) & 7;                                      \
        af[ks][mm] = *(const bf16x8*)((const char*)lds + (abuf) * 16384 + p_ * 128 + (cb_ ^ (f_ << 4))); \
      }                                                                     \
      _Pragma("unroll")                                                     \
      for (int nn = 0; nn < 4; ++nn){                                       \
        int o_ = wc * 64 + nn * 16 + (l & 15);                              \
        int f_ = (o_ ^ (o_ >> 3)) & 7;                                      \
        bfr[ks][nn] = *(const bf16x8*)((const char*)lds + 32768 + (wbuf) * 32768 + o_ * 128 + (cb_ ^ (f_ << 4))); \
      }                                                                     \
    }                                                                       \
  } while (0)

#define MFMA32() do {                                                       \
    __builtin_amdgcn_s_setprio(1);                                          \
    _Pragma("unroll")                                                       \
    for (int ks = 0; ks < 2; ++ks)                                          \
      _Pragma("unroll")                                                     \
      for (int mm = 0; mm < 4; ++mm)                                        \
        _Pragma("unroll")                                                   \
        for (int nn = 0; nn < 4; ++nn)                                      \
          acc[mm][nn] = __builtin_amdgcn_mfma_f32_16x16x32_bf16(            \
              af[ks][mm], bfr[ks][nn], acc[mm][nn], 0, 0, 0);               \
    __builtin_amdgcn_s_setprio(0);                                          \
  } while (0)

// One K-tile: single barrier, deep prefetch.
// rLd: reg set receiving feat(t+2); rWr: reg set holding feat(t+1).
#define TILE(abuf, wsel, wnext, rLd, rWr, ftK, wtK) do {                    \
    READ_FRAGS((abuf), (wsel));                                             \
    FEAT_LOAD(rLd, (ftK));                   /* feat(t+2) issued first */   \
    __builtin_amdgcn_sched_barrier(0);                                      \
    asm volatile("s_waitcnt lgkmcnt(0)" ::: "memory");                      \
    __builtin_amdgcn_sched_barrier(0);                                      \
    MFMA32();                                                               \
    FEAT_WRITE((abuf) ^ 1, rWr);             /* scoreboard waits feat(t+1) */ \
    WT_DMA((wnext), (wtK));                  /* wt(t+2) issued last */      \
    __builtin_amdgcn_sched_barrier(0);                                      \
    asm volatile("s_waitcnt vmcnt(8)" ::: "memory");  /* retire wt(t+1) */  \
    asm volatile("s_waitcnt lgkmcnt(0)" ::: "memory");                      \
    __builtin_amdgcn_s_barrier();                                           \
  } while (0)

  // prologue: feat(0)->rA, wt(0)->buf0, feat(1)->rB, wt(1)->buf1
  FEAT_LOAD(rA, 0);
  WT_DMA(0, 0);
  FEAT_LOAD(rB, 64);
  WT_DMA(1, 64);
  __builtin_amdgcn_sched_barrier(0);
  FEAT_WRITE(0, rA);                         // waits feat(0) only
  asm volatile("s_waitcnt vmcnt(8)" ::: "memory");   // retire wt(0); feat(1)+wt(1) fly
  asm volatile("s_waitcnt lgkmcnt(0)" ::: "memory");
  __builtin_amdgcn_s_barrier();

  {
    bf16x8 af[2][4], bfr[2][4];
    int w0 = 0;                                // w0 = t%3 for even t of the pair
    #pragma unroll 1
    for (int it2 = 0; it2 < 16; ++it2){
      int te = it2 << 1;                       // even tile: abuf 0, rWr=rB, rLd=rA
      int ftE = (te + 2 < 32 ? te + 2 : 31) << 6;
      int w1 = w0 + 1 > 2 ? 0 : w0 + 1;        // (te+1)%3
      int w2 = w1 + 1 > 2 ? 0 : w1 + 1;        // (te+2)%3
      TILE(0, w0, w2, rA, rB, ftE, ftE);
      int to = te + 1;                         // odd tile: abuf 1, rWr=rA, rLd=rB
      int ftO = (to + 2 < 32 ? to + 2 : 31) << 6;
      TILE(1, w1, w0, rB, rA, ftO, ftO);
      w0 = w2;                                 // (te+2)%3 for next pair
    }
  }
  __syncthreads();   // drains vmcnt(0)+lgkm: safe to reuse LDS

  // epilogue: transpose 128p x 256o into lds as [128p][512B], coalesced Zt write
  #pragma unroll
  for (int m = 0; m < 4; ++m){
    #pragma unroll
    for (int n = 0; n < 4; ++n){
      int o_c = wc * 64 + n * 16 + (l & 15);
      #pragma unroll
      for (int r = 0; r < 4; ++r){
        int p_ = wr * 64 + m * 16 + (l >> 4) * 4 + r;
        *(unsigned short*)((char*)lds + p_ * 512 + ((o_c * 2) ^ ((p_ & 7) << 4))) =
            f2bf(acc[m][n][r]);
      }
    }
  }
  __syncthreads();
  {
    int p = t >> 2, seg = t & 3;
    size_t rowb = ((size_t)(bb * 4096 + p0g + p)) * 1024 + (size_t)o0 * 2 + seg * 128;
    int swz = (p & 7) << 4;
    #pragma unroll
    for (int j = 0; j < 8; ++j){
      int y = (seg * 128 + j * 16) ^ swz;
      f32x4 v = *(const f32x4*)((char*)lds + p * 512 + y);
      *(f32x4*)((char*)zt + rowb + j * 16) = v;
    }
  }
#undef FEAT_LOAD
#undef FEAT_WRITE
#undef WT_DMA
#undef READ_FRAGS
#undef MFMA32
#undef TILE
}

// ---------- K2: ROI gather on Zt (512 ch) + BN1 + ReLU -> h1 bf16 [6272][512] ----------
__global__ __launch_bounds__(256) void roi_gather_kernel(
    const unsigned short* __restrict__ zt, const float* __restrict__ boxes,
    const float* __restrict__ sc1, const float* __restrict__ sh1,
    unsigned short* __restrict__ h1)
{
  int ky = blockIdx.x, roi = blockIdx.y;
  __shared__ int   sIdx[16][8];
  __shared__ float sW[16][8];
  int t = threadIdx.x;

  int   b   = (int)boxes[roi * 5 + 0];
  float bx1 = boxes[roi * 5 + 1], by1 = boxes[roi * 5 + 2];
  float bx2 = boxes[roi * 5 + 3], by2 = boxes[roi * 5 + 4];
  float rw = fmaxf(bx2 - bx1, 1.f), rh = fmaxf(by2 - by1, 1.f);
  float bw = rw * (1.f / 7.f), bh = rh * (1.f / 7.f);

  if (t < 28){
    int kx = t >> 2, s = t & 3;
    int sy = s >> 1, sx = s & 1;
    float yy = by1 + ((float)ky + ((float)sy + 0.5f) * 0.5f) * bh;
    float xx = bx1 + ((float)kx + ((float)sx + 0.5f) * 0.5f) * bw;
    bool vy = (yy >= -1.f) && (yy <= 64.f);
    bool vx = (xx >= -1.f) && (xx <= 64.f);
    float yc = fminf(fmaxf(yy, 0.f), 63.f);
    float xc = fminf(fmaxf(xx, 0.f), 63.f);
    int iy0 = (int)yc, ix0 = (int)xc;
    int iy1 = min(iy0 + 1, 63), ix1 = min(ix0 + 1, 63);
    float fy = yc - (float)iy0, fx = xc - (float)ix0;
    float v = (vy && vx) ? 0.25f : 0.f;
    float wy0 = 1.f - fy, wx0 = 1.f - fx;
    sIdx[s * 4 + 0][kx] = iy0 * 64 + ix0;  sW[s * 4 + 0][kx] = wy0 * wx0 * v;
    sIdx[s * 4 + 1][kx] = iy0 * 64 + ix1;  sW[s * 4 + 1][kx] = wy0 * fx  * v;
    sIdx[s * 4 + 2][kx] = iy1 * 64 + ix0;  sW[s * 4 + 2][kx] = fy  * wx0 * v;
    sIdx[s * 4 + 3][kx] = iy1 * 64 + ix1;  sW[s * 4 + 3][kx] = fy  * fx  * v;
  }
  __syncthreads();

  int w = t >> 6, l = t & 63;
  f32x4 s0 = *(const f32x4*)(sc1 + l * 8);
  f32x4 s1 = *(const f32x4*)(sc1 + l * 8 + 4);
  f32x4 h0 = *(const f32x4*)(sh1 + l * 8);
  f32x4 hh = *(const f32x4*)(sh1 + l * 8 + 4);
  const unsigned short* zb = zt + ((size_t)b * 4096) * 512 + l * 8;

  for (int kx = w; kx < 7; kx += 4){
    float a[8];
    #pragma unroll
    for (int j = 0; j < 8; ++j) a[j] = 0.f;
    #pragma unroll
    for (int i = 0; i < 16; ++i){
      int idx = sIdx[i][kx];
      float wt = sW[i][kx];
      u16x8 v = *(const u16x8*)(zb + (size_t)idx * 512);
      #pragma unroll
      for (int j = 0; j < 8; ++j) a[j] += wt * bf16_to_f32(v[j]);
    }
    u16x8 o;
    #pragma unroll
    for (int j = 0; j < 4; ++j){
      float v0 = fmaxf(a[j] * s0[j] + h0[j], 0.f);
      float v1 = fmaxf(a[j + 4] * s1[j] + hh[j], 0.f);
      o[j] = f2bf(v0);
      o[j + 4] = f2bf(v1);
    }
    *(u16x8*)(h1 + ((size_t)(roi * 49 + ky * 7 + kx)) * 512 + l * 8) = o;
  }
}

// ---------- K3: bf16 GEMM, B-transposed input, fused scale/shift + ReLU ----------
template<int BM, int BN>
__global__ __launch_bounds__(256) void gemm_bt_relu(
    const unsigned short* __restrict__ A, const unsigned short* __restrict__ Bt,
    const float* __restrict__ scale, const float* __restrict__ shift,
    unsigned short* __restrict__ C, int M, int N, int K)
{
  constexpr int BK = 64;
  constexpr int FM = BM / 32;
  constexpr int FN = BN / 32;
  __shared__ unsigned short lds_a[BM * BK];
  __shared__ unsigned short lds_b[BN * BK];
  int t = threadIdx.x;
  int l = t & 63, wid = t >> 6;
  int wr = wid >> 1, wc = wid & 1;
  int m0 = blockIdx.y * BM, n0 = blockIdx.x * BN;

  f32x4 acc[FM][FN];
  f32x4 z = {0.f, 0.f, 0.f, 0.f};
  #pragma unroll
  for (int m = 0; m < FM; ++m)
    #pragma unroll
    for (int n = 0; n < FN; ++n) acc[m][n] = z;

  const unsigned short* Ab = A  + (size_t)m0 * K;
  const unsigned short* Bb = Bt + (size_t)n0 * K;

  for (int kt = 0; kt < K; kt += BK){
    #pragma unroll
    for (int r = 0; r < BM / 32; ++r){
      int row = r * 32 + (t >> 3);
      GLOAD_LDS16(Ab + (size_t)row * K + kt + (t & 7) * 8,
                  lds_a + row * BK + (t & 7) * 8);
    }
    #pragma unroll
    for (int r = 0; r < BN / 32; ++r){
      int row = r * 32 + (t >> 3);
      GLOAD_LDS16(Bb + (size_t)row * K + kt + (t & 7) * 8,
                  lds_b + row * BK + (t & 7) * 8);
    }
    __syncthreads();
    #pragma unroll
    for (int ks = 0; ks < 2; ++ks){
      bf16x8 af[FM], bfr[FN];
      #pragma unroll
      for (int m = 0; m < FM; ++m)
        af[m] = *reinterpret_cast<const bf16x8*>(
            lds_a + (wr * (BM / 2) + m * 16 + (l & 15)) * BK + ks * 32 + (l >> 4) * 8);
      #pragma unroll
      for (int n = 0; n < FN; ++n)
        bfr[n] = *reinterpret_cast<const bf16x8*>(
            lds_b + (wc * (BN / 2) + n * 16 + (l & 15)) * BK + ks * 32 + (l >> 4) * 8);
      #pragma unroll
      for (int m = 0; m < FM; ++m)
        #pragma unroll
        for (int n = 0; n < FN; ++n)
          acc[m][n] = __builtin_amdgcn_mfma_f32_16x16x32_bf16(af[m], bfr[n], acc[m][n], 0, 0, 0);
    }
    __syncthreads();
  }

  #pragma unroll
  for (int m = 0; m < FM; ++m){
    int gr = m0 + wr * (BM / 2) + m * 16 + (l >> 4) * 4;
    #pragma unroll
    for (int n = 0; n < FN; ++n){
      int gc = n0 + wc * (BN / 2) + n * 16 + (l & 15);
      float sc = scale[gc], sh = shift[gc];
      #pragma unroll
      for (int r = 0; r < 4; ++r){
        float v = acc[m][n][r] * sc + sh;
        v = fmaxf(v, 0.f);
        C[(size_t)(gr + r) * N + gc] = f2bf(v);
      }
    }
  }
}

// ---------- K4: mean over 49 bins -> out f32 [128][256] ----------
__global__ __launch_bounds__(256) void reduce_kernel(
    const unsigned short* __restrict__ h2, float* __restrict__ out)
{
  int n = blockIdx.x, o = threadIdx.x;
  const unsigned short* p = h2 + (size_t)n * 49 * 256 + o;
  float s = 0.f;
  for (int j = 0; j < 49; ++j) s += bf16_to_f32(p[j * 256]);
  out[n * 256 + o] = s * (1.f / 49.f);
}

// ---------- launch ----------
extern "C" void kernel_launch(void* const* d_in, const int* in_sizes, int n_in,
                              void* d_out, int out_size, void* d_ws, size_t ws_size,
                              hipStream_t stream)
{
  const float* feat  = (const float*)d_in[0];
  const float* boxes = (const float*)d_in[1];
  const float* w1  = (const float*)d_in[2];
  const float* b1  = (const float*)d_in[3];
  const float* g1  = (const float*)d_in[4];
  const float* be1 = (const float*)d_in[5];
  const float* m1  = (const float*)d_in[6];
  const float* v1  = (const float*)d_in[7];
  const float* w2  = (const float*)d_in[8];
  const float* b2  = (const float*)d_in[9];
  const float* g2  = (const float*)d_in[10];
  const float* be2 = (const float*)d_in[11];
  const float* m2  = (const float*)d_in[12];
  const float* v2  = (const float*)d_in[13];
  float* out = (float*)d_out;

  char* ws = (char*)d_ws;
  unsigned short* w1s = (unsigned short*)(ws);                         // 2 MB (pre-swizzled)
  unsigned short* w2b = (unsigned short*)(ws + (2u << 20));            // 256 KB
  float* sc1 = (float*)(ws + (2u << 20) + (256u << 10));
  float* sh1 = sc1 + 512;
  float* sc2 = sh1 + 512;
  float* sh2 = sc2 + 256;
  unsigned short* zt = (unsigned short*)(ws + (4u  << 20));            // 16.8 MB
  unsigned short* h1 = (unsigned short*)(ws + (24u << 20));            // 6.4 MB
  unsigned short* h2 = (unsigned short*)(ws + (32u << 20));            // 3.2 MB

  hipLaunchKernelGGL(prep_kernel, dim3(256), dim3(256), 0, stream,
                     w1, w2, b1, g1, be1, m1, v1, b2, g2, be2, m2, v2,
                     w1s, w2b, sc1, sh1, sc2, sh2);
  hipLaunchKernelGGL(conv1_kernel, dim3(256), dim3(512), 0, stream,
                     w1s, feat, zt);
  hipLaunchKernelGGL(roi_gather_kernel, dim3(7, 128), dim3(256), 0, stream,
                     zt, boxes, sc1, sh1, h1);
  hipLaunchKernelGGL(HIP_KERNEL_NAME(gemm_bt_relu<64, 64>),
                     dim3(256 / 64, 6272 / 64), dim3(256), 0, stream,
                     h1, w2b, sc2, sh2, h2, 6272, 256, 512);
  hipLaunchKernelGGL(reduce_kernel, dim3(128), dim3(256), 0, stream, h2, out);
}

// Round 13
// 80.046 us; speedup vs baseline: 1.6691x; 1.0058x over previous
//
#include <hip/hip_runtime.h>

// ---------- helpers ----------
typedef __bf16 bf16x8 __attribute__((ext_vector_type(8)));
typedef float  f32x4  __attribute__((ext_vector_type(4)));
typedef unsigned short u16x8 __attribute__((ext_vector_type(8)));
typedef unsigned int u32;
typedef unsigned long long u64;

static __device__ __forceinline__ unsigned short f2bf(float f){
  __bf16 b = (__bf16)f;                     // native RTNE cvt; pairs into v_cvt_pk_bf16_f32
  return *(unsigned short*)&b;
}
static __device__ __forceinline__ float bf16_to_f32(unsigned short h){
  return __uint_as_float(((unsigned)h) << 16);
}

#define GLOAD_LDS16(g, l)                                                        \
  __builtin_amdgcn_global_load_lds((const __attribute__((address_space(1))) void*)(g), \
                                   (__attribute__((address_space(3))) void*)(l), 16, 0, 0)

// ---------- K0: weight conversion + BN folding ----------
__global__ __launch_bounds__(256) void prep_kernel(
    const float* __restrict__ w1, const float* __restrict__ w2,
    const float* __restrict__ b1, const float* __restrict__ g1, const float* __restrict__ be1,
    const float* __restrict__ m1, const float* __restrict__ v1,
    const float* __restrict__ b2, const float* __restrict__ g2, const float* __restrict__ be2,
    const float* __restrict__ m2, const float* __restrict__ v2,
    unsigned short* __restrict__ w1s, unsigned short* __restrict__ w2b,
    float* __restrict__ sc1, float* __restrict__ sh1,
    float* __restrict__ sc2, float* __restrict__ sh2)
{
  int i = blockIdx.x * 256 + threadIdx.x;
  int stride = gridDim.x * 256;
  for (int k = i; k < 512 * 2048; k += stride){
    int o = k >> 11, c = k & 2047;
    int key = (o ^ (o >> 3)) & 7;
    w1s[(o << 11) | (c ^ (key << 3))] = f2bf(w1[k]);
  }
  for (int k = i; k < 256 * 512;  k += stride) w2b[k] = f2bf(w2[k]);
  if (i < 512){
    float s = g1[i] * rsqrtf(v1[i] + 1e-5f);
    sc1[i] = s;
    sh1[i] = (b1[i] - m1[i]) * s + be1[i];
  } else if (i - 512 < 256){
    int o = i - 512;
    float s = g2[o] * rsqrtf(v2[o] + 1e-5f);
    sc2[o] = s;
    sh2[o] = (b2[o] - m2[o]) * s + be2[o];
  }
}

// ---------- K1: conv1 full map: Zt[b*4096+p][512] = (W1.F)^T, bf16 ----------
// BM=128p x BN=256o x BK=64, 8 waves of 64x64, grid 256 (1 block/CU, all CUs).
// One barrier per K-tile, 32 MFMA per barrier. Deep prefetch: wt TRI-buffered
// (issued t for t+2, BEFORE the MFMA block); feat reg TRIPLE-set (distance 3).
// NO lgkm fence between frag reads and MFMA -- compiler emits fine-grained
// lgkmcnt(N) so the first MFMA starts after 2 frags. Steady-state vmem queue
// = 12 [feat(t+2)4, wt(t+2)4, feat(t+3)4]; one vmcnt(12)/tile retires wt(t+1).
// LDS bytes: A buf a @ a*16384 (16KB ea); wt buf w @ 32768 + w*32768 (32KB ea).
__global__ __launch_bounds__(512, 1) void conv1_kernel(
    const unsigned short* __restrict__ w1s,   // [512][2048] bf16 pre-swizzled
    const float* __restrict__ feat,           // [4][2048][4096] f32
    unsigned short* __restrict__ zt)          // [4*4096][512] bf16
{
  __shared__ unsigned short lds[65536];       // 128 KB
  int t = threadIdx.x, l = t & 63, wid = t >> 6;
  int wr = wid >> 2, wc = wid & 3;            // wave = 64p x 64o

  int lid = ((blockIdx.x & 7) << 5) | (blockIdx.x >> 3);  // bijective XCD swizzle
  int nt = lid & 1, mt = lid >> 1;            // o-halves adjacent on one XCD
  int bb = mt >> 5;
  int p0g = (mt & 31) << 7;
  int o0 = nt << 8;

  int c4 = (t >> 5) << 2;                     // feat: c-rows c4..c4+3
  int p4 = (t & 31) << 2;                     // f32x4 at p4
  const float* fBase = feat + ((size_t)(bb * 2048 + c4)) * 4096 + p0g + p4;

  const unsigned short* wBase = w1s + ((size_t)(o0 + (t >> 3))) * 2048 + (t & 7) * 8;
  int wDstOff = (t >> 3) * 64 + (t & 7) * 8;

  f32x4 acc[4][4];
  #pragma unroll
  for (int m = 0; m < 4; ++m)
    #pragma unroll
    for (int n = 0; n < 4; ++n){ f32x4 z4 = {0.f,0.f,0.f,0.f}; acc[m][n] = z4; }

  f32x4 r0[4], r1[4], r2[4];                  // feat depth-3 reg sets (static names)

#define FEAT_LOAD(dst, kt) do {                                             \
    _Pragma("unroll")                                                       \
    for (int i = 0; i < 4; ++i)                                             \
      dst[i] = *(const f32x4*)(fBase + (size_t)((kt) + i) * 4096);          \
  } while (0)

#define FEAT_WRITE(abuf, src) do {                                          \
    _Pragma("unroll")                                                       \
    for (int j = 0; j < 4; ++j){                                            \
      int p_ = p4 + j;                                                      \
      int f_ = (p_ ^ (p_ >> 3)) & 7;                                        \
      u32 lo_ = ((u32)f2bf(src[0][j])) | (((u32)f2bf(src[1][j])) << 16);    \
      u32 hi_ = ((u32)f2bf(src[2][j])) | (((u32)f2bf(src[3][j])) << 16);    \
      u64 v_ = ((u64)hi_ << 32) | lo_;                                      \
      *(u64*)((char*)lds + (abuf) * 16384 + p_ * 128 + ((c4 * 2) ^ (f_ << 4))) = v_; \
    }                                                                       \
  } while (0)

#define WT_DMA(wbuf, kt) do {                                               \
    _Pragma("unroll")                                                       \
    for (int i = 0; i < 4; ++i)                                             \
      GLOAD_LDS16(wBase + (kt) + (size_t)i * (64 * 2048),                   \
                  lds + 16384 + (wbuf) * 16384 + wDstOff + i * (64 * 64));  \
  } while (0)

#define READ_FRAGS(abuf, wbuf) do {                                         \
    _Pragma("unroll")                                                       \
    for (int ks = 0; ks < 2; ++ks){                                         \
      int cb_ = ks * 64 + (l >> 4) * 16;                                    \
      _Pragma("unroll")                                                     \
      for (int mm = 0; mm < 4; ++mm){                                       \
        int p_ = wr * 64 + mm * 16 + (l & 15);                              \
        int f_ = (p_ ^ (p_ >> 3)) & 7;                                      \
        af[ks][mm] = *(const bf16x8*)((const char*)lds + (abuf) * 16384 + p_ * 128 + (cb_ ^ (f_ << 4))); \
      }                                                                     \
      _Pragma("unroll")                                                     \
      for (int nn = 0; nn < 4; ++nn){                                       \
        int o_ = wc * 64 + nn * 16 + (l & 15);                              \
        int f_ = (o_ ^ (o_ >> 3)) & 7;                                      \
        bfr[ks][nn] = *(const bf16x8*)((const char*)lds + 32768 + (wbuf) * 32768 + o_ * 128 + (cb_ ^ (f_ << 4))); \
      }                                                                     \
    }                                                                       \
  } while (0)

#define MFMA32() do {                                                       \
    __builtin_amdgcn_s_setprio(1);                                          \
    _Pragma("unroll")                                                       \
    for (int ks = 0; ks < 2; ++ks)                                          \
      _Pragma("unroll")                                                     \
      for (int mm = 0; mm < 4; ++mm)                                        \
        _Pragma("unroll")                                                   \
        for (int nn = 0; nn < 4; ++nn)                                      \
          acc[mm][nn] = __builtin_amdgcn_mfma_f32_16x16x32_bf16(            \
              af[ks][mm], bfr[ks][nn], acc[mm][nn], 0, 0, 0);               \
    __builtin_amdgcn_s_setprio(0);                                          \
  } while (0)

// Tile tt: abuf=tt&1, wsel=tt%3, wnext=(tt+2)%3, rWr holds feat(tt+1),
// rLd receives feat(tt+3). No fence between frags and MFMA (compiler
// fine-grained lgkm); single vmcnt(12)+lgkm0 before the barrier.
#define TILE(abuf, wsel, wnext, rLd, rWr, ktW, ktF) do {                    \
    READ_FRAGS((abuf), (wsel));                                             \
    WT_DMA((wnext), (ktW));                                                 \
    FEAT_LOAD(rLd, (ktF));                                                  \
    MFMA32();                                                               \
    FEAT_WRITE((abuf) ^ 1, rWr);                                            \
    __builtin_amdgcn_sched_barrier(0);                                      \
    asm volatile("s_waitcnt vmcnt(12)" ::: "memory");                       \
    asm volatile("s_waitcnt lgkmcnt(0)" ::: "memory");                      \
    __builtin_amdgcn_s_barrier();                                           \
  } while (0)

#define KT(x) (((x) < 32 ? (x) : 31) << 6)

  // prologue: feat0->r0, wt0->buf0, feat1->r1, wt1->buf1, feat2->r2
  FEAT_LOAD(r0, 0);
  WT_DMA(0, 0);
  FEAT_LOAD(r1, KT(1));
  WT_DMA(1, KT(1));
  FEAT_LOAD(r2, KT(2));
  FEAT_WRITE(0, r0);                          // scoreboard waits feat0 only
  __builtin_amdgcn_sched_barrier(0);
  asm volatile("s_waitcnt vmcnt(12)" ::: "memory");   // retire wt0
  asm volatile("s_waitcnt lgkmcnt(0)" ::: "memory");
  __builtin_amdgcn_s_barrier();

  {
    bf16x8 af[2][4], bfr[2][4];
    #pragma unroll 1
    for (int i6 = 0; i6 < 5; ++i6){
      int b6 = i6 * 6;
      TILE(0, 0, 2, r0, r1, KT(b6 + 2), KT(b6 + 3));   // tile b6+0
      TILE(1, 1, 0, r1, r2, KT(b6 + 3), KT(b6 + 4));   // tile b6+1
      TILE(0, 2, 1, r2, r0, KT(b6 + 4), KT(b6 + 5));   // tile b6+2
      TILE(1, 0, 2, r0, r1, KT(b6 + 5), KT(b6 + 6));   // tile b6+3
      TILE(0, 1, 0, r1, r2, KT(b6 + 6), KT(b6 + 7));   // tile b6+4
      TILE(1, 2, 1, r2, r0, KT(b6 + 7), KT(b6 + 8));   // tile b6+5
    }
    TILE(0, 0, 2, r0, r1, KT(32), KT(33));             // tile 30
    TILE(1, 1, 0, r1, r2, KT(33), KT(34));             // tile 31
  }
  __syncthreads();   // full drain; LDS reused below

  // epilogue: transpose 128p x 256o into lds as [128p][512B], coalesced Zt write
  #pragma unroll
  for (int m = 0; m < 4; ++m){
    #pragma unroll
    for (int n = 0; n < 4; ++n){
      int o_c = wc * 64 + n * 16 + (l & 15);
      #pragma unroll
      for (int r = 0; r < 4; ++r){
        int p_ = wr * 64 + m * 16 + (l >> 4) * 4 + r;
        *(unsigned short*)((char*)lds + p_ * 512 + ((o_c * 2) ^ ((p_ & 7) << 4))) =
            f2bf(acc[m][n][r]);
      }
    }
  }
  __syncthreads();
  {
    int p = t >> 2, seg = t & 3;
    size_t rowb = ((size_t)(bb * 4096 + p0g + p)) * 1024 + (size_t)o0 * 2 + seg * 128;
    int swz = (p & 7) << 4;
    #pragma unroll
    for (int j = 0; j < 8; ++j){
      int y = (seg * 128 + j * 16) ^ swz;
      f32x4 v = *(const f32x4*)((char*)lds + p * 512 + y);
      *(f32x4*)((char*)zt + rowb + j * 16) = v;
    }
  }
#undef FEAT_LOAD
#undef FEAT_WRITE
#undef WT_DMA
#undef READ_FRAGS
#undef MFMA32
#undef TILE
#undef KT
}

// ---------- K2: ROI gather on Zt (512 ch) + BN1 + ReLU -> h1 bf16 [6272][512] ----------
__global__ __launch_bounds__(256) void roi_gather_kernel(
    const unsigned short* __restrict__ zt, const float* __restrict__ boxes,
    const float* __restrict__ sc1, const float* __restrict__ sh1,
    unsigned short* __restrict__ h1)
{
  int ky = blockIdx.x, roi = blockIdx.y;
  __shared__ int   sIdx[16][8];
  __shared__ float sW[16][8];
  int t = threadIdx.x;

  int   b   = (int)boxes[roi * 5 + 0];
  float bx1 = boxes[roi * 5 + 1], by1 = boxes[roi * 5 + 2];
  float bx2 = boxes[roi * 5 + 3], by2 = boxes[roi * 5 + 4];
  float rw = fmaxf(bx2 - bx1, 1.f), rh = fmaxf(by2 - by1, 1.f);
  float bw = rw * (1.f / 7.f), bh = rh * (1.f / 7.f);

  if (t < 28){
    int kx = t >> 2, s = t & 3;
    int sy = s >> 1, sx = s & 1;
    float yy = by1 + ((float)ky + ((float)sy + 0.5f) * 0.5f) * bh;
    float xx = bx1 + ((float)kx + ((float)sx + 0.5f) * 0.5f) * bw;
    bool vy = (yy >= -1.f) && (yy <= 64.f);
    bool vx = (xx >= -1.f) && (xx <= 64.f);
    float yc = fminf(fmaxf(yy, 0.f), 63.f);
    float xc = fminf(fmaxf(xx, 0.f), 63.f);
    int iy0 = (int)yc, ix0 = (int)xc;
    int iy1 = min(iy0 + 1, 63), ix1 = min(ix0 + 1, 63);
    float fy = yc - (float)iy0, fx = xc - (float)ix0;
    float v = (vy && vx) ? 0.25f : 0.f;
    float wy0 = 1.f - fy, wx0 = 1.f - fx;
    sIdx[s * 4 + 0][kx] = iy0 * 64 + ix0;  sW[s * 4 + 0][kx] = wy0 * wx0 * v;
    sIdx[s * 4 + 1][kx] = iy0 * 64 + ix1;  sW[s * 4 + 1][kx] = wy0 * fx  * v;
    sIdx[s * 4 + 2][kx] = iy1 * 64 + ix0;  sW[s * 4 + 2][kx] = fy  * wx0 * v;
    sIdx[s * 4 + 3][kx] = iy1 * 64 + ix1;  sW[s * 4 + 3][kx] = fy  * fx  * v;
  }
  __syncthreads();

  int w = t >> 6, l = t & 63;
  f32x4 s0 = *(const f32x4*)(sc1 + l * 8);
  f32x4 s1 = *(const f32x4*)(sc1 + l * 8 + 4);
  f32x4 h0 = *(const f32x4*)(sh1 + l * 8);
  f32x4 hh = *(const f32x4*)(sh1 + l * 8 + 4);
  const unsigned short* zb = zt + ((size_t)b * 4096) * 512 + l * 8;

  for (int kx = w; kx < 7; kx += 4){
    float a[8];
    #pragma unroll
    for (int j = 0; j < 8; ++j) a[j] = 0.f;
    #pragma unroll
    for (int i = 0; i < 16; ++i){
      int idx = sIdx[i][kx];
      float wt = sW[i][kx];
      u16x8 v = *(const u16x8*)(zb + (size_t)idx * 512);
      #pragma unroll
      for (int j = 0; j < 8; ++j) a[j] += wt * bf16_to_f32(v[j]);
    }
    u16x8 o;
    #pragma unroll
    for (int j = 0; j < 4; ++j){
      float v0 = fmaxf(a[j] * s0[j] + h0[j], 0.f);
      float v1 = fmaxf(a[j + 4] * s1[j] + hh[j], 0.f);
      o[j] = f2bf(v0);
      o[j + 4] = f2bf(v1);
    }
    *(u16x8*)(h1 + ((size_t)(roi * 49 + ky * 7 + kx)) * 512 + l * 8) = o;
  }
}

// ---------- K3: bf16 GEMM, B-transposed input, fused scale/shift + ReLU ----------
template<int BM, int BN>
__global__ __launch_bounds__(256) void gemm_bt_relu(
    const unsigned short* __restrict__ A, const unsigned short* __restrict__ Bt,
    const float* __restrict__ scale, const float* __restrict__ shift,
    unsigned short* __restrict__ C, int M, int N, int K)
{
  constexpr int BK = 64;
  constexpr int FM = BM / 32;
  constexpr int FN = BN / 32;
  __shared__ unsigned short lds_a[BM * BK];
  __shared__ unsigned short lds_b[BN * BK];
  int t = threadIdx.x;
  int l = t & 63, wid = t >> 6;
  int wr = wid >> 1, wc = wid & 1;
  int m0 = blockIdx.y * BM, n0 = blockIdx.x * BN;

  f32x4 acc[FM][FN];
  f32x4 z = {0.f, 0.f, 0.f, 0.f};
  #pragma unroll
  for (int m = 0; m < FM; ++m)
    #pragma unroll
    for (int n = 0; n < FN; ++n) acc[m][n] = z;

  const unsigned short* Ab = A  + (size_t)m0 * K;
  const unsigned short* Bb = Bt + (size_t)n0 * K;

  for (int kt = 0; kt < K; kt += BK){
    #pragma unroll
    for (int r = 0; r < BM / 32; ++r){
      int row = r * 32 + (t >> 3);
      GLOAD_LDS16(Ab + (size_t)row * K + kt + (t & 7) * 8,
                  lds_a + row * BK + (t & 7) * 8);
    }
    #pragma unroll
    for (int r = 0; r < BN / 32; ++r){
      int row = r * 32 + (t >> 3);
      GLOAD_LDS16(Bb + (size_t)row * K + kt + (t & 7) * 8,
                  lds_b + row * BK + (t & 7) * 8);
    }
    __syncthreads();
    #pragma unroll
    for (int ks = 0; ks < 2; ++ks){
      bf16x8 af[FM], bfr[FN];
      #pragma unroll
      for (int m = 0; m < FM; ++m)
        af[m] = *reinterpret_cast<const bf16x8*>(
            lds_a + (wr * (BM / 2) + m * 16 + (l & 15)) * BK + ks * 32 + (l >> 4) * 8);
      #pragma unroll
      for (int n = 0; n < FN; ++n)
        bfr[n] = *reinterpret_cast<const bf16x8*>(
            lds_b + (wc * (BN / 2) + n * 16 + (l & 15)) * BK + ks * 32 + (l >> 4) * 8);
      #pragma unroll
      for (int m = 0; m < FM; ++m)
        #pragma unroll
        for (int n = 0; n < FN; ++n)
          acc[m][n] = __builtin_amdgcn_mfma_f32_16x16x32_bf16(af[m], bfr[n], acc[m][n], 0, 0, 0);
    }
    __syncthreads();
  }

  #pragma unroll
  for (int m = 0; m < FM; ++m){
    int gr = m0 + wr * (BM / 2) + m * 16 + (l >> 4) * 4;
    #pragma unroll
    for (int n = 0; n < FN; ++n){
      int gc = n0 + wc * (BN / 2) + n * 16 + (l & 15);
      float sc = scale[gc], sh = shift[gc];
      #pragma unroll
      for (int r = 0; r < 4; ++r){
        float v = acc[m][n][r] * sc + sh;
        v = fmaxf(v, 0.f);
        C[(size_t)(gr + r) * N + gc] = f2bf(v);
      }
    }
  }
}

// ---------- K4: mean over 49 bins -> out f32 [128][256] ----------
__global__ __launch_bounds__(256) void reduce_kernel(
    const unsigned short* __restrict__ h2, float* __restrict__ out)
{
  int n = blockIdx.x, o = threadIdx.x;
  const unsigned short* p = h2 + (size_t)n * 49 * 256 + o;
  float s = 0.f;
  for (int j = 0; j < 49; ++j) s += bf16_to_f32(p[j * 256]);
  out[n * 256 + o] = s * (1.f / 49.f);
}

// ---------- launch ----------
extern "C" void kernel_launch(void* const* d_in, const int* in_sizes, int n_in,
                              void* d_out, int out_size, void* d_ws, size_t ws_size,
                              hipStream_t stream)
{
  const float* feat  = (const float*)d_in[0];
  const float* boxes = (const float*)d_in[1];
  const float* w1  = (const float*)d_in[2];
  const float* b1  = (const float*)d_in[3];
  const float* g1  = (const float*)d_in[4];
  const float* be1 = (const float*)d_in[5];
  const float* m1  = (const float*)d_in[6];
  const float* v1  = (const float*)d_in[7];
  const float* w2  = (const float*)d_in[8];
  const float* b2  = (const float*)d_in[9];
  const float* g2  = (const float*)d_in[10];
  const float* be2 = (const float*)d_in[11];
  const float* m2  = (const float*)d_in[12];
  const float* v2  = (const float*)d_in[13];
  float* out = (float*)d_out;

  char* ws = (char*)d_ws;
  unsigned short* w1s = (unsigned short*)(ws);                         // 2 MB (pre-swizzled)
  unsigned short* w2b = (unsigned short*)(ws + (2u << 20));            // 256 KB
  float* sc1 = (float*)(ws + (2u << 20) + (256u << 10));
  float* sh1 = sc1 + 512;
  float* sc2 = sh1 + 512;
  float* sh2 = sc2 + 256;
  unsigned short* zt = (unsigned short*)(ws + (4u  << 20));            // 16.8 MB
  unsigned short* h1 = (unsigned short*)(ws + (24u << 20));            // 6.4 MB
  unsigned short* h2 = (unsigned short*)(ws + (32u << 20));            // 3.2 MB

  hipLaunchKernelGGL(prep_kernel, dim3(256), dim3(256), 0, stream,
                     w1, w2, b1, g1, be1, m1, v1, b2, g2, be2, m2, v2,
                     w1s, w2b, sc1, sh1, sc2, sh2);
  hipLaunchKernelGGL(conv1_kernel, dim3(256), dim3(512), 0, stream,
                     w1s, feat, zt);
  hipLaunchKernelGGL(roi_gather_kernel, dim3(7, 128), dim3(256), 0, stream,
                     zt, boxes, sc1, sh1, h1);
  hipLaunchKernelGGL(HIP_KERNEL_NAME(gemm_bt_relu<64, 64>),
                     dim3(256 / 64, 6272 / 64), dim3(256), 0, stream,
                     h1, w2b, sc2, sh2, h2, 6272, 256, 512);
  hipLaunchKernelGGL(reduce_kernel, dim3(128), dim3(256), 0, stream, h2, out);
}

// Round 14
// 75.865 us; speedup vs baseline: 1.7611x; 1.0551x over previous
//
#include <hip/hip_runtime.h>

// ---------- helpers ----------
typedef __bf16 bf16x8 __attribute__((ext_vector_type(8)));
typedef float  f32x4  __attribute__((ext_vector_type(4)));
typedef unsigned short u16x8 __attribute__((ext_vector_type(8)));
typedef unsigned int u32;
typedef unsigned long long u64;

static __device__ __forceinline__ unsigned short f2bf(float f){
  __bf16 b = (__bf16)f;                     // native RTNE cvt; pairs into v_cvt_pk_bf16_f32
  return *(unsigned short*)&b;
}
static __device__ __forceinline__ float bf16_to_f32(unsigned short h){
  return __uint_as_float(((unsigned)h) << 16);
}

#define GLOAD_LDS16(g, l)                                                        \
  __builtin_amdgcn_global_load_lds((const __attribute__((address_space(1))) void*)(g), \
                                   (__attribute__((address_space(3))) void*)(l), 16, 0, 0)

// ---------- K0: weight conversion + BN folding ----------
__global__ __launch_bounds__(256) void prep_kernel(
    const float* __restrict__ w1, const float* __restrict__ w2,
    const float* __restrict__ b1, const float* __restrict__ g1, const float* __restrict__ be1,
    const float* __restrict__ m1, const float* __restrict__ v1,
    const float* __restrict__ b2, const float* __restrict__ g2, const float* __restrict__ be2,
    const float* __restrict__ m2, const float* __restrict__ v2,
    unsigned short* __restrict__ w1s, unsigned short* __restrict__ w2b,
    float* __restrict__ sc1, float* __restrict__ sh1,
    float* __restrict__ sc2, float* __restrict__ sh2)
{
  int i = blockIdx.x * 256 + threadIdx.x;
  int stride = gridDim.x * 256;
  for (int k = i; k < 512 * 2048; k += stride){
    int o = k >> 11, c = k & 2047;
    int key = (o ^ (o >> 3)) & 7;
    w1s[(o << 11) | (c ^ (key << 3))] = f2bf(w1[k]);
  }
  for (int k = i; k < 256 * 512;  k += stride) w2b[k] = f2bf(w2[k]);
  if (i < 512){
    float s = g1[i] * rsqrtf(v1[i] + 1e-5f);
    sc1[i] = s;
    sh1[i] = (b1[i] - m1[i]) * s + be1[i];
  } else if (i - 512 < 256){
    int o = i - 512;
    float s = g2[o] * rsqrtf(v2[o] + 1e-5f);
    sc2[o] = s;
    sh2[o] = (b2[o] - m2[o]) * s + be2[o];
  }
}

// ---------- K1: conv1 full map (R13 structure, frozen best-known) ----------
__global__ __launch_bounds__(512, 1) void conv1_kernel(
    const unsigned short* __restrict__ w1s,   // [512][2048] bf16 pre-swizzled
    const float* __restrict__ feat,           // [4][2048][4096] f32
    unsigned short* __restrict__ zt)          // [4*4096][512] bf16
{
  __shared__ unsigned short lds[65536];       // 128 KB
  int t = threadIdx.x, l = t & 63, wid = t >> 6;
  int wr = wid >> 2, wc = wid & 3;            // wave = 64p x 64o

  int lid = ((blockIdx.x & 7) << 5) | (blockIdx.x >> 3);  // bijective XCD swizzle
  int nt = lid & 1, mt = lid >> 1;
  int bb = mt >> 5;
  int p0g = (mt & 31) << 7;
  int o0 = nt << 8;

  int c4 = (t >> 5) << 2;
  int p4 = (t & 31) << 2;
  const float* fBase = feat + ((size_t)(bb * 2048 + c4)) * 4096 + p0g + p4;

  const unsigned short* wBase = w1s + ((size_t)(o0 + (t >> 3))) * 2048 + (t & 7) * 8;
  int wDstOff = (t >> 3) * 64 + (t & 7) * 8;

  f32x4 acc[4][4];
  #pragma unroll
  for (int m = 0; m < 4; ++m)
    #pragma unroll
    for (int n = 0; n < 4; ++n){ f32x4 z4 = {0.f,0.f,0.f,0.f}; acc[m][n] = z4; }

  f32x4 r0[4], r1[4], r2[4];

#define FEAT_LOAD(dst, kt) do {                                             \
    _Pragma("unroll")                                                       \
    for (int i = 0; i < 4; ++i)                                             \
      dst[i] = *(const f32x4*)(fBase + (size_t)((kt) + i) * 4096);          \
  } while (0)

#define FEAT_WRITE(abuf, src) do {                                          \
    _Pragma("unroll")                                                       \
    for (int j = 0; j < 4; ++j){                                            \
      int p_ = p4 + j;                                                      \
      int f_ = (p_ ^ (p_ >> 3)) & 7;                                        \
      u32 lo_ = ((u32)f2bf(src[0][j])) | (((u32)f2bf(src[1][j])) << 16);    \
      u32 hi_ = ((u32)f2bf(src[2][j])) | (((u32)f2bf(src[3][j])) << 16);    \
      u64 v_ = ((u64)hi_ << 32) | lo_;                                      \
      *(u64*)((char*)lds + (abuf) * 16384 + p_ * 128 + ((c4 * 2) ^ (f_ << 4))) = v_; \
    }                                                                       \
  } while (0)

#define WT_DMA(wbuf, kt) do {                                               \
    _Pragma("unroll")                                                       \
    for (int i = 0; i < 4; ++i)                                             \
      GLOAD_LDS16(wBase + (kt) + (size_t)i * (64 * 2048),                   \
                  lds + 16384 + (wbuf) * 16384 + wDstOff + i * (64 * 64));  \
  } while (0)

#define READ_FRAGS(abuf, wbuf) do {                                         \
    _Pragma("unroll")                                                       \
    for (int ks = 0; ks < 2; ++ks){                                         \
      int cb_ = ks * 64 + (l >> 4) * 16;                                    \
      _Pragma("unroll")                                                     \
      for (int mm = 0; mm < 4; ++mm){                                       \
        int p_ = wr * 64 + mm * 16 + (l & 15);                              \
        int f_ = (p_ ^ (p_ >> 3)) & 7;                                      \
        af[ks][mm] = *(const bf16x8*)((const char*)lds + (abuf) * 16384 + p_ * 128 + (cb_ ^ (f_ << 4))); \
      }                                                                     \
      _Pragma("unroll")                                                     \
      for (int nn = 0; nn < 4; ++nn){                                       \
        int o_ = wc * 64 + nn * 16 + (l & 15);                              \
        int f_ = (o_ ^ (o_ >> 3)) & 7;                                      \
        bfr[ks][nn] = *(const bf16x8*)((const char*)lds + 32768 + (wbuf) * 32768 + o_ * 128 + (cb_ ^ (f_ << 4))); \
      }                                                                     \
    }                                                                       \
  } while (0)

#define MFMA32() do {                                                       \
    __builtin_amdgcn_s_setprio(1);                                          \
    _Pragma("unroll")                                                       \
    for (int ks = 0; ks < 2; ++ks)                                          \
      _Pragma("unroll")                                                     \
      for (int mm = 0; mm < 4; ++mm)                                        \
        _Pragma("unroll")                                                   \
        for (int nn = 0; nn < 4; ++nn)                                      \
          acc[mm][nn] = __builtin_amdgcn_mfma_f32_16x16x32_bf16(            \
              af[ks][mm], bfr[ks][nn], acc[mm][nn], 0, 0, 0);               \
    __builtin_amdgcn_s_setprio(0);                                          \
  } while (0)

#define TILE(abuf, wsel, wnext, rLd, rWr, ktW, ktF) do {                    \
    READ_FRAGS((abuf), (wsel));                                             \
    WT_DMA((wnext), (ktW));                                                 \
    FEAT_LOAD(rLd, (ktF));                                                  \
    MFMA32();                                                               \
    FEAT_WRITE((abuf) ^ 1, rWr);                                            \
    __builtin_amdgcn_sched_barrier(0);                                      \
    asm volatile("s_waitcnt vmcnt(12)" ::: "memory");                       \
    asm volatile("s_waitcnt lgkmcnt(0)" ::: "memory");                      \
    __builtin_amdgcn_s_barrier();                                           \
  } while (0)

#define KT(x) (((x) < 32 ? (x) : 31) << 6)

  FEAT_LOAD(r0, 0);
  WT_DMA(0, 0);
  FEAT_LOAD(r1, KT(1));
  WT_DMA(1, KT(1));
  FEAT_LOAD(r2, KT(2));
  FEAT_WRITE(0, r0);
  __builtin_amdgcn_sched_barrier(0);
  asm volatile("s_waitcnt vmcnt(12)" ::: "memory");
  asm volatile("s_waitcnt lgkmcnt(0)" ::: "memory");
  __builtin_amdgcn_s_barrier();

  {
    bf16x8 af[2][4], bfr[2][4];
    #pragma unroll 1
    for (int i6 = 0; i6 < 5; ++i6){
      int b6 = i6 * 6;
      TILE(0, 0, 2, r0, r1, KT(b6 + 2), KT(b6 + 3));
      TILE(1, 1, 0, r1, r2, KT(b6 + 3), KT(b6 + 4));
      TILE(0, 2, 1, r2, r0, KT(b6 + 4), KT(b6 + 5));
      TILE(1, 0, 2, r0, r1, KT(b6 + 5), KT(b6 + 6));
      TILE(0, 1, 0, r1, r2, KT(b6 + 6), KT(b6 + 7));
      TILE(1, 2, 1, r2, r0, KT(b6 + 7), KT(b6 + 8));
    }
    TILE(0, 0, 2, r0, r1, KT(32), KT(33));
    TILE(1, 1, 0, r1, r2, KT(33), KT(34));
  }
  __syncthreads();

  #pragma unroll
  for (int m = 0; m < 4; ++m){
    #pragma unroll
    for (int n = 0; n < 4; ++n){
      int o_c = wc * 64 + n * 16 + (l & 15);
      #pragma unroll
      for (int r = 0; r < 4; ++r){
        int p_ = wr * 64 + m * 16 + (l >> 4) * 4 + r;
        *(unsigned short*)((char*)lds + p_ * 512 + ((o_c * 2) ^ ((p_ & 7) << 4))) =
            f2bf(acc[m][n][r]);
      }
    }
  }
  __syncthreads();
  {
    int p = t >> 2, seg = t & 3;
    size_t rowb = ((size_t)(bb * 4096 + p0g + p)) * 1024 + (size_t)o0 * 2 + seg * 128;
    int swz = (p & 7) << 4;
    #pragma unroll
    for (int j = 0; j < 8; ++j){
      int y = (seg * 128 + j * 16) ^ swz;
      f32x4 v = *(const f32x4*)((char*)lds + p * 512 + y);
      *(f32x4*)((char*)zt + rowb + j * 16) = v;
    }
  }
#undef FEAT_LOAD
#undef FEAT_WRITE
#undef WT_DMA
#undef READ_FRAGS
#undef MFMA32
#undef TILE
#undef KT
}

// ---------- K2: ROI gather on Zt (512 ch) + BN1 + ReLU -> h1 bf16 [6272][512] ----------
__global__ __launch_bounds__(256) void roi_gather_kernel(
    const unsigned short* __restrict__ zt, const float* __restrict__ boxes,
    const float* __restrict__ sc1, const float* __restrict__ sh1,
    unsigned short* __restrict__ h1)
{
  int ky = blockIdx.x, roi = blockIdx.y;
  __shared__ int   sIdx[16][8];
  __shared__ float sW[16][8];
  int t = threadIdx.x;

  int   b   = (int)boxes[roi * 5 + 0];
  float bx1 = boxes[roi * 5 + 1], by1 = boxes[roi * 5 + 2];
  float bx2 = boxes[roi * 5 + 3], by2 = boxes[roi * 5 + 4];
  float rw = fmaxf(bx2 - bx1, 1.f), rh = fmaxf(by2 - by1, 1.f);
  float bw = rw * (1.f / 7.f), bh = rh * (1.f / 7.f);

  if (t < 28){
    int kx = t >> 2, s = t & 3;
    int sy = s >> 1, sx = s & 1;
    float yy = by1 + ((float)ky + ((float)sy + 0.5f) * 0.5f) * bh;
    float xx = bx1 + ((float)kx + ((float)sx + 0.5f) * 0.5f) * bw;
    bool vy = (yy >= -1.f) && (yy <= 64.f);
    bool vx = (xx >= -1.f) && (xx <= 64.f);
    float yc = fminf(fmaxf(yy, 0.f), 63.f);
    float xc = fminf(fmaxf(xx, 0.f), 63.f);
    int iy0 = (int)yc, ix0 = (int)xc;
    int iy1 = min(iy0 + 1, 63), ix1 = min(ix0 + 1, 63);
    float fy = yc - (float)iy0, fx = xc - (float)ix0;
    float v = (vy && vx) ? 0.25f : 0.f;
    float wy0 = 1.f - fy, wx0 = 1.f - fx;
    sIdx[s * 4 + 0][kx] = iy0 * 64 + ix0;  sW[s * 4 + 0][kx] = wy0 * wx0 * v;
    sIdx[s * 4 + 1][kx] = iy0 * 64 + ix1;  sW[s * 4 + 1][kx] = wy0 * fx  * v;
    sIdx[s * 4 + 2][kx] = iy1 * 64 + ix0;  sW[s * 4 + 2][kx] = fy  * wx0 * v;
    sIdx[s * 4 + 3][kx] = iy1 * 64 + ix1;  sW[s * 4 + 3][kx] = fy  * fx  * v;
  }
  __syncthreads();

  int w = t >> 6, l = t & 63;
  f32x4 s0 = *(const f32x4*)(sc1 + l * 8);
  f32x4 s1 = *(const f32x4*)(sc1 + l * 8 + 4);
  f32x4 h0 = *(const f32x4*)(sh1 + l * 8);
  f32x4 hh = *(const f32x4*)(sh1 + l * 8 + 4);
  const unsigned short* zb = zt + ((size_t)b * 4096) * 512 + l * 8;

  for (int kx = w; kx < 7; kx += 4){
    float a[8];
    #pragma unroll
    for (int j = 0; j < 8; ++j) a[j] = 0.f;
    #pragma unroll
    for (int i = 0; i < 16; ++i){
      int idx = sIdx[i][kx];
      float wt = sW[i][kx];
      u16x8 v = *(const u16x8*)(zb + (size_t)idx * 512);
      #pragma unroll
      for (int j = 0; j < 8; ++j) a[j] += wt * bf16_to_f32(v[j]);
    }
    u16x8 o;
    #pragma unroll
    for (int j = 0; j < 4; ++j){
      float v0 = fmaxf(a[j] * s0[j] + h0[j], 0.f);
      float v1 = fmaxf(a[j + 4] * s1[j] + hh[j], 0.f);
      o[j] = f2bf(v0);
      o[j + 4] = f2bf(v1);
    }
    *(u16x8*)(h1 + ((size_t)(roi * 49 + ky * 7 + kx)) * 512 + l * 8) = o;
  }
}

// ---------- K3: fused gemm2 + BN2 + ReLU + mean-over-49-bins -> out f32 ----------
// One ROI per block-row: A-tile = 64 rows starting at roi*49 (rows 49..63 are
// pad, masked out of the mean; their loads stay inside d_ws). grid (4, 128).
// Epilogue: per-lane masked partial sums -> LDS [64 col][8 part] -> mean ->
// out[roi][o0+col] f32. Eliminates h2 buffer + reduce kernel.
__global__ __launch_bounds__(256) void gemm2_fused_kernel(
    const unsigned short* __restrict__ A,    // h1 [6272][512] bf16
    const unsigned short* __restrict__ Bt,   // w2b [256][512] bf16
    const float* __restrict__ scale, const float* __restrict__ shift,
    float* __restrict__ out)                 // [128][256] f32
{
  constexpr int BK = 64;
  __shared__ unsigned short lds_a[64 * BK];
  __shared__ unsigned short lds_b[64 * BK];
  __shared__ float lds_r[64][8];
  int t = threadIdx.x;
  int l = t & 63, wid = t >> 6;
  int wr = wid >> 1, wc = wid & 1;
  int roi = blockIdx.y;
  int n0 = blockIdx.x * 64;

  f32x4 acc[2][2];
  f32x4 z = {0.f, 0.f, 0.f, 0.f};
  #pragma unroll
  for (int m = 0; m < 2; ++m)
    #pragma unroll
    for (int n = 0; n < 2; ++n) acc[m][n] = z;

  const unsigned short* Ab = A  + (size_t)(roi * 49) * 512;
  const unsigned short* Bb = Bt + (size_t)n0 * 512;

  for (int kt = 0; kt < 512; kt += BK){
    {
      int row = (t >> 3) & 63;       // two passes of 32 rows via r-loop
      #pragma unroll
      for (int r = 0; r < 2; ++r){
        int rr = r * 32 + (t >> 3);
        GLOAD_LDS16(Ab + (size_t)rr * 512 + kt + (t & 7) * 8,
                    lds_a + rr * BK + (t & 7) * 8);
        GLOAD_LDS16(Bb + (size_t)rr * 512 + kt + (t & 7) * 8,
                    lds_b + rr * BK + (t & 7) * 8);
      }
      (void)row;
    }
    __syncthreads();
    #pragma unroll
    for (int ks = 0; ks < 2; ++ks){
      bf16x8 af[2], bfr[2];
      #pragma unroll
      for (int m = 0; m < 2; ++m)
        af[m] = *reinterpret_cast<const bf16x8*>(
            lds_a + (wr * 32 + m * 16 + (l & 15)) * BK + ks * 32 + (l >> 4) * 8);
      #pragma unroll
      for (int n = 0; n < 2; ++n)
        bfr[n] = *reinterpret_cast<const bf16x8*>(
            lds_b + (wc * 32 + n * 16 + (l & 15)) * BK + ks * 32 + (l >> 4) * 8);
      #pragma unroll
      for (int m = 0; m < 2; ++m)
        #pragma unroll
        for (int n = 0; n < 2; ++n)
          acc[m][n] = __builtin_amdgcn_mfma_f32_16x16x32_bf16(af[m], bfr[n], acc[m][n], 0, 0, 0);
    }
    __syncthreads();
  }

  // masked BN+ReLU+partial-sum over this lane's 8 rows, per column
  #pragma unroll
  for (int n = 0; n < 2; ++n){
    int col = wc * 32 + n * 16 + (l & 15);          // 0..63
    int gc = n0 + col;
    float sc = scale[gc], sh = shift[gc];
    float ps = 0.f;
    #pragma unroll
    for (int m = 0; m < 2; ++m){
      int lr0 = wr * 32 + m * 16 + (l >> 4) * 4;    // local row of acc[..][0]
      #pragma unroll
      for (int r = 0; r < 4; ++r){
        int lr = lr0 + r;
        float v = fmaxf(acc[m][n][r] * sc + sh, 0.f);
        ps += (lr < 49) ? v : 0.f;
      }
    }
    // partial slot: contributors per col = wr(2) x (l>>4)(4) = 8
    lds_r[col][wr * 4 + (l >> 4)] = (n == 0) ? ps : lds_r[col][wr * 4 + (l >> 4)];
    if (n == 1) lds_r[col][wr * 4 + (l >> 4)] += 0.f;  // placeholder; handled below
    if (n == 0) ; // first write done above
    if (n == 1){
      // accumulate second n into same slot (same col? no -- different col). store directly:
    }
  }
  // NOTE: the two n-values map to DIFFERENT columns, so each (col, slot) is
  // written exactly once per n. Redo cleanly:
  __syncthreads();
  #pragma unroll
  for (int n = 0; n < 2; ++n){
    int col = wc * 32 + n * 16 + (l & 15);
    int gc = n0 + col;
    float sc = scale[gc], sh = shift[gc];
    float ps = 0.f;
    #pragma unroll
    for (int m = 0; m < 2; ++m){
      int lr0 = wr * 32 + m * 16 + (l >> 4) * 4;
      #pragma unroll
      for (int r = 0; r < 4; ++r){
        int lr = lr0 + r;
        float v = fmaxf(acc[m][n][r] * sc + sh, 0.f);
        ps += (lr < 49) ? v : 0.f;
      }
    }
    lds_r[col][wr * 4 + (l >> 4)] = ps;
    __syncthreads();
    if (t < 64){
      float s = 0.f;
      #pragma unroll
      for (int q = 0; q < 8; ++q) s += lds_r[t][q];
      int cc = (t & 15) | ((t >> 4) == (unsigned)0 ? 0 : 0);  // t is col only if mapping matches
      // columns for this n: {wc*32 + n*16 + 0..15} over wc in {0,1} -> t covers 0..63,
      // but only columns congruent to this n's set are valid THIS iteration.
      int colset_lo = n * 16;                // cols [n*16, n*16+16) and [32+n*16, ...)
      bool valid = ((t & 31) >= colset_lo) && ((t & 31) < colset_lo + 16);
      if (valid) out[roi * 256 + n0 + t] = s * (1.f / 49.f);
    }
    __syncthreads();
  }
}

// ---------- launch ----------
extern "C" void kernel_launch(void* const* d_in, const int* in_sizes, int n_in,
                              void* d_out, int out_size, void* d_ws, size_t ws_size,
                              hipStream_t stream)
{
  const float* feat  = (const float*)d_in[0];
  const float* boxes = (const float*)d_in[1];
  const float* w1  = (const float*)d_in[2];
  const float* b1  = (const float*)d_in[3];
  const float* g1  = (const float*)d_in[4];
  const float* be1 = (const float*)d_in[5];
  const float* m1  = (const float*)d_in[6];
  const float* v1  = (const float*)d_in[7];
  const float* w2  = (const float*)d_in[8];
  const float* b2  = (const float*)d_in[9];
  const float* g2  = (const float*)d_in[10];
  const float* be2 = (const float*)d_in[11];
  const float* m2  = (const float*)d_in[12];
  const float* v2  = (const float*)d_in[13];
  float* out = (float*)d_out;

  char* ws = (char*)d_ws;
  unsigned short* w1s = (unsigned short*)(ws);                         // 2 MB (pre-swizzled)
  unsigned short* w2b = (unsigned short*)(ws + (2u << 20));            // 256 KB
  float* sc1 = (float*)(ws + (2u << 20) + (256u << 10));
  float* sh1 = sc1 + 512;
  float* sc2 = sh1 + 512;
  float* sh2 = sc2 + 256;
  unsigned short* zt = (unsigned short*)(ws + (4u  << 20));            // 16.8 MB
  unsigned short* h1 = (unsigned short*)(ws + (24u << 20));            // 6.4 MB (+pad slack to 32MB)

  hipLaunchKernelGGL(prep_kernel, dim3(1024), dim3(256), 0, stream,
                     w1, w2, b1, g1, be1, m1, v1, b2, g2, be2, m2, v2,
                     w1s, w2b, sc1, sh1, sc2, sh2);
  hipLaunchKernelGGL(conv1_kernel, dim3(256), dim3(512), 0, stream,
                     w1s, feat, zt);
  hipLaunchKernelGGL(roi_gather_kernel, dim3(7, 128), dim3(256), 0, stream,
                     zt, boxes, sc1, sh1, h1);
  hipLaunchKernelGGL(gemm2_fused_kernel, dim3(4, 128), dim3(256), 0, stream,
                     h1, w2b, sc2, sh2, out);
}

// Round 15
// 75.717 us; speedup vs baseline: 1.7645x; 1.0019x over previous
//
#include <hip/hip_runtime.h>

// ---------- helpers ----------
typedef __bf16 bf16x8 __attribute__((ext_vector_type(8)));
typedef float  f32x4  __attribute__((ext_vector_type(4)));
typedef unsigned short u16x8 __attribute__((ext_vector_type(8)));
typedef unsigned int u32;
typedef unsigned long long u64;

static __device__ __forceinline__ unsigned short f2bf(float f){
  __bf16 b = (__bf16)f;                     // native RTNE cvt; pairs into v_cvt_pk_bf16_f32
  return *(unsigned short*)&b;
}
static __device__ __forceinline__ float bf16_to_f32(unsigned short h){
  return __uint_as_float(((unsigned)h) << 16);
}

#define GLOAD_LDS16(g, l)                                                        \
  __builtin_amdgcn_global_load_lds((const __attribute__((address_space(1))) void*)(g), \
                                   (__attribute__((address_space(3))) void*)(l), 16, 0, 0)

// ---------- K0: weight conversion + BN folding ----------
__global__ __launch_bounds__(256) void prep_kernel(
    const float* __restrict__ w1, const float* __restrict__ w2,
    const float* __restrict__ b1, const float* __restrict__ g1, const float* __restrict__ be1,
    const float* __restrict__ m1, const float* __restrict__ v1,
    const float* __restrict__ b2, const float* __restrict__ g2, const float* __restrict__ be2,
    const float* __restrict__ m2, const float* __restrict__ v2,
    unsigned short* __restrict__ w1s, unsigned short* __restrict__ w2b,
    float* __restrict__ sc1, float* __restrict__ sh1,
    float* __restrict__ sc2, float* __restrict__ sh2)
{
  int i = blockIdx.x * 256 + threadIdx.x;
  int stride = gridDim.x * 256;
  for (int k = i; k < 512 * 2048; k += stride){
    int o = k >> 11, c = k & 2047;
    int key = (o ^ (o >> 3)) & 7;
    w1s[(o << 11) | (c ^ (key << 3))] = f2bf(w1[k]);
  }
  for (int k = i; k < 256 * 512;  k += stride) w2b[k] = f2bf(w2[k]);
  if (i < 512){
    float s = g1[i] * rsqrtf(v1[i] + 1e-5f);
    sc1[i] = s;
    sh1[i] = (b1[i] - m1[i]) * s + be1[i];
  } else if (i - 512 < 256){
    int o = i - 512;
    float s = g2[o] * rsqrtf(v2[o] + 1e-5f);
    sc2[o] = s;
    sh2[o] = (b2[o] - m2[o]) * s + be2[o];
  }
}

// ---------- K1: conv1 full map (R13 structure, frozen best-known) ----------
__global__ __launch_bounds__(512, 1) void conv1_kernel(
    const unsigned short* __restrict__ w1s,   // [512][2048] bf16 pre-swizzled
    const float* __restrict__ feat,           // [4][2048][4096] f32
    unsigned short* __restrict__ zt)          // [4*4096][512] bf16
{
  __shared__ unsigned short lds[65536];       // 128 KB
  int t = threadIdx.x, l = t & 63, wid = t >> 6;
  int wr = wid >> 2, wc = wid & 3;            // wave = 64p x 64o

  int lid = ((blockIdx.x & 7) << 5) | (blockIdx.x >> 3);  // bijective XCD swizzle
  int nt = lid & 1, mt = lid >> 1;
  int bb = mt >> 5;
  int p0g = (mt & 31) << 7;
  int o0 = nt << 8;

  int c4 = (t >> 5) << 2;
  int p4 = (t & 31) << 2;
  const float* fBase = feat + ((size_t)(bb * 2048 + c4)) * 4096 + p0g + p4;

  const unsigned short* wBase = w1s + ((size_t)(o0 + (t >> 3))) * 2048 + (t & 7) * 8;
  int wDstOff = (t >> 3) * 64 + (t & 7) * 8;

  f32x4 acc[4][4];
  #pragma unroll
  for (int m = 0; m < 4; ++m)
    #pragma unroll
    for (int n = 0; n < 4; ++n){ f32x4 z4 = {0.f,0.f,0.f,0.f}; acc[m][n] = z4; }

  f32x4 r0[4], r1[4], r2[4];

#define FEAT_LOAD(dst, kt) do {                                             \
    _Pragma("unroll")                                                       \
    for (int i = 0; i < 4; ++i)                                             \
      dst[i] = *(const f32x4*)(fBase + (size_t)((kt) + i) * 4096);          \
  } while (0)

#define FEAT_WRITE(abuf, src) do {                                          \
    _Pragma("unroll")                                                       \
    for (int j = 0; j < 4; ++j){                                            \
      int p_ = p4 + j;                                                      \
      int f_ = (p_ ^ (p_ >> 3)) & 7;                                        \
      u32 lo_ = ((u32)f2bf(src[0][j])) | (((u32)f2bf(src[1][j])) << 16);    \
      u32 hi_ = ((u32)f2bf(src[2][j])) | (((u32)f2bf(src[3][j])) << 16);    \
      u64 v_ = ((u64)hi_ << 32) | lo_;                                      \
      *(u64*)((char*)lds + (abuf) * 16384 + p_ * 128 + ((c4 * 2) ^ (f_ << 4))) = v_; \
    }                                                                       \
  } while (0)

#define WT_DMA(wbuf, kt) do {                                               \
    _Pragma("unroll")                                                       \
    for (int i = 0; i < 4; ++i)                                             \
      GLOAD_LDS16(wBase + (kt) + (size_t)i * (64 * 2048),                   \
                  lds + 16384 + (wbuf) * 16384 + wDstOff + i * (64 * 64));  \
  } while (0)

#define READ_FRAGS(abuf, wbuf) do {                                         \
    _Pragma("unroll")                                                       \
    for (int ks = 0; ks < 2; ++ks){                                         \
      int cb_ = ks * 64 + (l >> 4) * 16;                                    \
      _Pragma("unroll")                                                     \
      for (int mm = 0; mm < 4; ++mm){                                       \
        int p_ = wr * 64 + mm * 16 + (l & 15);                              \
        int f_ = (p_ ^ (p_ >> 3)) & 7;                                      \
        af[ks][mm] = *(const bf16x8*)((const char*)lds + (abuf) * 16384 + p_ * 128 + (cb_ ^ (f_ << 4))); \
      }                                                                     \
      _Pragma("unroll")                                                     \
      for (int nn = 0; nn < 4; ++nn){                                       \
        int o_ = wc * 64 + nn * 16 + (l & 15);                              \
        int f_ = (o_ ^ (o_ >> 3)) & 7;                                      \
        bfr[ks][nn] = *(const bf16x8*)((const char*)lds + 32768 + (wbuf) * 32768 + o_ * 128 + (cb_ ^ (f_ << 4))); \
      }                                                                     \
    }                                                                       \
  } while (0)

#define MFMA32() do {                                                       \
    __builtin_amdgcn_s_setprio(1);                                          \
    _Pragma("unroll")                                                       \
    for (int ks = 0; ks < 2; ++ks)                                          \
      _Pragma("unroll")                                                     \
      for (int mm = 0; mm < 4; ++mm)                                        \
        _Pragma("unroll")                                                   \
        for (int nn = 0; nn < 4; ++nn)                                      \
          acc[mm][nn] = __builtin_amdgcn_mfma_f32_16x16x32_bf16(            \
              af[ks][mm], bfr[ks][nn], acc[mm][nn], 0, 0, 0);               \
    __builtin_amdgcn_s_setprio(0);                                          \
  } while (0)

#define TILE(abuf, wsel, wnext, rLd, rWr, ktW, ktF) do {                    \
    READ_FRAGS((abuf), (wsel));                                             \
    WT_DMA((wnext), (ktW));                                                 \
    FEAT_LOAD(rLd, (ktF));                                                  \
    MFMA32();                                                               \
    FEAT_WRITE((abuf) ^ 1, rWr);                                            \
    __builtin_amdgcn_sched_barrier(0);                                      \
    asm volatile("s_waitcnt vmcnt(12)" ::: "memory");                       \
    asm volatile("s_waitcnt lgkmcnt(0)" ::: "memory");                      \
    __builtin_amdgcn_s_barrier();                                           \
  } while (0)

#define KT(x) (((x) < 32 ? (x) : 31) << 6)

  FEAT_LOAD(r0, 0);
  WT_DMA(0, 0);
  FEAT_LOAD(r1, KT(1));
  WT_DMA(1, KT(1));
  FEAT_LOAD(r2, KT(2));
  FEAT_WRITE(0, r0);
  __builtin_amdgcn_sched_barrier(0);
  asm volatile("s_waitcnt vmcnt(12)" ::: "memory");
  asm volatile("s_waitcnt lgkmcnt(0)" ::: "memory");
  __builtin_amdgcn_s_barrier();

  {
    bf16x8 af[2][4], bfr[2][4];
    #pragma unroll 1
    for (int i6 = 0; i6 < 5; ++i6){
      int b6 = i6 * 6;
      TILE(0, 0, 2, r0, r1, KT(b6 + 2), KT(b6 + 3));
      TILE(1, 1, 0, r1, r2, KT(b6 + 3), KT(b6 + 4));
      TILE(0, 2, 1, r2, r0, KT(b6 + 4), KT(b6 + 5));
      TILE(1, 0, 2, r0, r1, KT(b6 + 5), KT(b6 + 6));
      TILE(0, 1, 0, r1, r2, KT(b6 + 6), KT(b6 + 7));
      TILE(1, 2, 1, r2, r0, KT(b6 + 7), KT(b6 + 8));
    }
    TILE(0, 0, 2, r0, r1, KT(32), KT(33));
    TILE(1, 1, 0, r1, r2, KT(33), KT(34));
  }
  __syncthreads();

  #pragma unroll
  for (int m = 0; m < 4; ++m){
    #pragma unroll
    for (int n = 0; n < 4; ++n){
      int o_c = wc * 64 + n * 16 + (l & 15);
      #pragma unroll
      for (int r = 0; r < 4; ++r){
        int p_ = wr * 64 + m * 16 + (l >> 4) * 4 + r;
        *(unsigned short*)((char*)lds + p_ * 512 + ((o_c * 2) ^ ((p_ & 7) << 4))) =
            f2bf(acc[m][n][r]);
      }
    }
  }
  __syncthreads();
  {
    int p = t >> 2, seg = t & 3;
    size_t rowb = ((size_t)(bb * 4096 + p0g + p)) * 1024 + (size_t)o0 * 2 + seg * 128;
    int swz = (p & 7) << 4;
    #pragma unroll
    for (int j = 0; j < 8; ++j){
      int y = (seg * 128 + j * 16) ^ swz;
      f32x4 v = *(const f32x4*)((char*)lds + p * 512 + y);
      *(f32x4*)((char*)zt + rowb + j * 16) = v;
    }
  }
#undef FEAT_LOAD
#undef FEAT_WRITE
#undef WT_DMA
#undef READ_FRAGS
#undef MFMA32
#undef TILE
#undef KT
}

// ---------- K2: ROI gather on Zt (512 ch) + BN1 + ReLU -> h1 bf16 [6272][512] ----------
__global__ __launch_bounds__(256) void roi_gather_kernel(
    const unsigned short* __restrict__ zt, const float* __restrict__ boxes,
    const float* __restrict__ sc1, const float* __restrict__ sh1,
    unsigned short* __restrict__ h1)
{
  int ky = blockIdx.x, roi = blockIdx.y;
  __shared__ int   sIdx[16][8];
  __shared__ float sW[16][8];
  int t = threadIdx.x;

  int   b   = (int)boxes[roi * 5 + 0];
  float bx1 = boxes[roi * 5 + 1], by1 = boxes[roi * 5 + 2];
  float bx2 = boxes[roi * 5 + 3], by2 = boxes[roi * 5 + 4];
  float rw = fmaxf(bx2 - bx1, 1.f), rh = fmaxf(by2 - by1, 1.f);
  float bw = rw * (1.f / 7.f), bh = rh * (1.f / 7.f);

  if (t < 28){
    int kx = t >> 2, s = t & 3;
    int sy = s >> 1, sx = s & 1;
    float yy = by1 + ((float)ky + ((float)sy + 0.5f) * 0.5f) * bh;
    float xx = bx1 + ((float)kx + ((float)sx + 0.5f) * 0.5f) * bw;
    bool vy = (yy >= -1.f) && (yy <= 64.f);
    bool vx = (xx >= -1.f) && (xx <= 64.f);
    float yc = fminf(fmaxf(yy, 0.f), 63.f);
    float xc = fminf(fmaxf(xx, 0.f), 63.f);
    int iy0 = (int)yc, ix0 = (int)xc;
    int iy1 = min(iy0 + 1, 63), ix1 = min(ix0 + 1, 63);
    float fy = yc - (float)iy0, fx = xc - (float)ix0;
    float v = (vy && vx) ? 0.25f : 0.f;
    float wy0 = 1.f - fy, wx0 = 1.f - fx;
    sIdx[s * 4 + 0][kx] = iy0 * 64 + ix0;  sW[s * 4 + 0][kx] = wy0 * wx0 * v;
    sIdx[s * 4 + 1][kx] = iy0 * 64 + ix1;  sW[s * 4 + 1][kx] = wy0 * fx  * v;
    sIdx[s * 4 + 2][kx] = iy1 * 64 + ix0;  sW[s * 4 + 2][kx] = fy  * wx0 * v;
    sIdx[s * 4 + 3][kx] = iy1 * 64 + ix1;  sW[s * 4 + 3][kx] = fy  * fx  * v;
  }
  __syncthreads();

  int w = t >> 6, l = t & 63;
  f32x4 s0 = *(const f32x4*)(sc1 + l * 8);
  f32x4 s1 = *(const f32x4*)(sc1 + l * 8 + 4);
  f32x4 h0 = *(const f32x4*)(sh1 + l * 8);
  f32x4 hh = *(const f32x4*)(sh1 + l * 8 + 4);
  const unsigned short* zb = zt + ((size_t)b * 4096) * 512 + l * 8;

  for (int kx = w; kx < 7; kx += 4){
    float a[8];
    #pragma unroll
    for (int j = 0; j < 8; ++j) a[j] = 0.f;
    #pragma unroll
    for (int i = 0; i < 16; ++i){
      int idx = sIdx[i][kx];
      float wt = sW[i][kx];
      u16x8 v = *(const u16x8*)(zb + (size_t)idx * 512);
      #pragma unroll
      for (int j = 0; j < 8; ++j) a[j] += wt * bf16_to_f32(v[j]);
    }
    u16x8 o;
    #pragma unroll
    for (int j = 0; j < 4; ++j){
      float v0 = fmaxf(a[j] * s0[j] + h0[j], 0.f);
      float v1 = fmaxf(a[j + 4] * s1[j] + hh[j], 0.f);
      o[j] = f2bf(v0);
      o[j + 4] = f2bf(v1);
    }
    *(u16x8*)(h1 + ((size_t)(roi * 49 + ky * 7 + kx)) * 512 + l * 8) = o;
  }
}

// ---------- K3: fused gemm2 + BN2 + ReLU + mean-over-49-bins -> out f32 ----------
// One ROI per block-row: A-tile = 64 rows at roi*49 (rows 49..63 pad, masked
// from the mean; loads stay inside d_ws). grid (4, 128), 4 waves (2x2 of 32x32).
// Epilogue: per-lane masked partial sums -> lds_r[64 col][8 slots] -> 32 lanes
// per n-half reduce 8 slots -> out[roi][n0+col] f32.
__global__ __launch_bounds__(256) void gemm2_fused_kernel(
    const unsigned short* __restrict__ A,    // h1 [6272][512] bf16
    const unsigned short* __restrict__ Bt,   // w2b [256][512] bf16
    const float* __restrict__ scale, const float* __restrict__ shift,
    float* __restrict__ out)                 // [128][256] f32
{
  constexpr int BK = 64;
  __shared__ unsigned short lds_a[64 * BK];
  __shared__ unsigned short lds_b[64 * BK];
  __shared__ float lds_r[64][8];
  int t = threadIdx.x;
  int l = t & 63, wid = t >> 6;
  int wr = wid >> 1, wc = wid & 1;
  int roi = blockIdx.y;
  int n0 = blockIdx.x * 64;

  f32x4 acc[2][2];
  f32x4 z = {0.f, 0.f, 0.f, 0.f};
  #pragma unroll
  for (int m = 0; m < 2; ++m)
    #pragma unroll
    for (int n = 0; n < 2; ++n) acc[m][n] = z;

  const unsigned short* Ab = A  + (size_t)(roi * 49) * 512;
  const unsigned short* Bb = Bt + (size_t)n0 * 512;

  for (int kt = 0; kt < 512; kt += BK){
    #pragma unroll
    for (int r = 0; r < 2; ++r){
      int rr = r * 32 + (t >> 3);
      GLOAD_LDS16(Ab + (size_t)rr * 512 + kt + (t & 7) * 8,
                  lds_a + rr * BK + (t & 7) * 8);
      GLOAD_LDS16(Bb + (size_t)rr * 512 + kt + (t & 7) * 8,
                  lds_b + rr * BK + (t & 7) * 8);
    }
    __syncthreads();
    #pragma unroll
    for (int ks = 0; ks < 2; ++ks){
      bf16x8 af[2], bfr[2];
      #pragma unroll
      for (int m = 0; m < 2; ++m)
        af[m] = *reinterpret_cast<const bf16x8*>(
            lds_a + (wr * 32 + m * 16 + (l & 15)) * BK + ks * 32 + (l >> 4) * 8);
      #pragma unroll
      for (int n = 0; n < 2; ++n)
        bfr[n] = *reinterpret_cast<const bf16x8*>(
            lds_b + (wc * 32 + n * 16 + (l & 15)) * BK + ks * 32 + (l >> 4) * 8);
      #pragma unroll
      for (int m = 0; m < 2; ++m)
        #pragma unroll
        for (int n = 0; n < 2; ++n)
          acc[m][n] = __builtin_amdgcn_mfma_f32_16x16x32_bf16(af[m], bfr[n], acc[m][n], 0, 0, 0);
    }
    __syncthreads();
  }

  // masked BN+ReLU+mean epilogue (single clean pass per n)
  #pragma unroll
  for (int n = 0; n < 2; ++n){
    int col = wc * 32 + n * 16 + (l & 15);          // 32 distinct cols this n
    int gc = n0 + col;
    float sc = scale[gc], sh = shift[gc];
    float ps = 0.f;
    #pragma unroll
    for (int m = 0; m < 2; ++m){
      int lr0 = wr * 32 + m * 16 + (l >> 4) * 4;
      #pragma unroll
      for (int r = 0; r < 4; ++r){
        int lr = lr0 + r;
        float v = fmaxf(acc[m][n][r] * sc + sh, 0.f);
        ps += (lr < 49) ? v : 0.f;
      }
    }
    lds_r[col][wr * 4 + (l >> 4)] = ps;             // 256 distinct (col,slot) writes
    __syncthreads();
    if (t < 32){
      int c2 = (t >> 4) * 32 + n * 16 + (t & 15);   // this n's 32 columns
      float s = 0.f;
      #pragma unroll
      for (int q = 0; q < 8; ++q) s += lds_r[c2][q];
      out[roi * 256 + n0 + c2] = s * (1.f / 49.f);
    }
    __syncthreads();
  }
}

// ---------- launch ----------
extern "C" void kernel_launch(void* const* d_in, const int* in_sizes, int n_in,
                              void* d_out, int out_size, void* d_ws, size_t ws_size,
                              hipStream_t stream)
{
  const float* feat  = (const float*)d_in[0];
  const float* boxes = (const float*)d_in[1];
  const float* w1  = (const float*)d_in[2];
  const float* b1  = (const float*)d_in[3];
  const float* g1  = (const float*)d_in[4];
  const float* be1 = (const float*)d_in[5];
  const float* m1  = (const float*)d_in[6];
  const float* v1  = (const float*)d_in[7];
  const float* w2  = (const float*)d_in[8];
  const float* b2  = (const float*)d_in[9];
  const float* g2  = (const float*)d_in[10];
  const float* be2 = (const float*)d_in[11];
  const float* m2  = (const float*)d_in[12];
  const float* v2  = (const float*)d_in[13];
  float* out = (float*)d_out;

  char* ws = (char*)d_ws;
  unsigned short* w1s = (unsigned short*)(ws);                         // 2 MB (pre-swizzled)
  unsigned short* w2b = (unsigned short*)(ws + (2u << 20));            // 256 KB
  float* sc1 = (float*)(ws + (2u << 20) + (256u << 10));
  float* sh1 = sc1 + 512;
  float* sc2 = sh1 + 512;
  float* sh2 = sc2 + 256;
  unsigned short* zt = (unsigned short*)(ws + (4u  << 20));            // 16.8 MB
  unsigned short* h1 = (unsigned short*)(ws + (24u << 20));            // 6.4 MB (+pad slack)

  hipLaunchKernelGGL(prep_kernel, dim3(1024), dim3(256), 0, stream,
                     w1, w2, b1, g1, be1, m1, v1, b2, g2, be2, m2, v2,
                     w1s, w2b, sc1, sh1, sc2, sh2);
  hipLaunchKernelGGL(conv1_kernel, dim3(256), dim3(512), 0, stream,
                     w1s, feat, zt);
  hipLaunchKernelGGL(roi_gather_kernel, dim3(7, 128), dim3(256), 0, stream,
                     zt, boxes, sc1, sh1, h1);
  hipLaunchKernelGGL(gemm2_fused_kernel, dim3(4, 128), dim3(256), 0, stream,
                     h1, w2b, sc2, sh2, out);
}